// Round 1
// baseline (638.929 us; speedup 1.0000x reference)
//
#include <hip/hip_runtime.h>
#include <hip/hip_bf16.h>
#include <math.h>

#define NNODES 50000
#define IN_DIM 256
#define HID 64
#define HEADS 4
#define OUT_DIM 40
#define NEDGES 800000
#define ETOT (NEDGES + NNODES)
#define NEG_SLOPE 0.2f

__device__ __forceinline__ float wave_reduce_max(float v) {
    #pragma unroll
    for (int off = 32; off > 0; off >>= 1) v = fmaxf(v, __shfl_xor(v, off));
    return v;
}
__device__ __forceinline__ float wave_reduce_sum(float v) {
    #pragma unroll
    for (int off = 32; off > 0; off >>= 1) v += __shfl_xor(v, off);
    return v;
}

// ---------------- GEMM1: h1[M,256] = x[M,256] @ W1[256,256] ----------------
__global__ __launch_bounds__(256) void gemm1_kernel(const float* __restrict__ A,
                                                    const float* __restrict__ B,
                                                    float* __restrict__ C, int M) {
    __shared__ float As[16][64];  // [k][m] transposed
    __shared__ float Bs[16][64];  // [k][n]
    int tid = threadIdx.x;
    int tx = tid & 15, ty = tid >> 4;
    int m0 = blockIdx.y * 64, n0 = blockIdx.x * 64;
    float acc[4][4] = {};
    for (int k0 = 0; k0 < 256; k0 += 16) {
        {
            int r = tid >> 2;          // 0..63 (m)
            int c = (tid & 3) << 2;    // 0,4,8,12 (k)
            float4 v = make_float4(0.f, 0.f, 0.f, 0.f);
            int row = m0 + r;
            if (row < M) v = *reinterpret_cast<const float4*>(A + (size_t)row * 256 + k0 + c);
            As[c + 0][r] = v.x; As[c + 1][r] = v.y; As[c + 2][r] = v.z; As[c + 3][r] = v.w;
        }
        {
            int r = tid >> 4;          // 0..15 (k)
            int c = (tid & 15) << 2;   // 0..60 (n)
            float4 v = *reinterpret_cast<const float4*>(B + (size_t)(k0 + r) * 256 + n0 + c);
            *reinterpret_cast<float4*>(&Bs[r][c]) = v;
        }
        __syncthreads();
        #pragma unroll
        for (int k = 0; k < 16; ++k) {
            float a[4], b[4];
            #pragma unroll
            for (int i = 0; i < 4; i++) a[i] = As[k][ty * 4 + i];
            #pragma unroll
            for (int j = 0; j < 4; j++) b[j] = Bs[k][tx * 4 + j];
            #pragma unroll
            for (int i = 0; i < 4; i++)
                #pragma unroll
                for (int j = 0; j < 4; j++) acc[i][j] += a[i] * b[j];
        }
        __syncthreads();
    }
    #pragma unroll
    for (int i = 0; i < 4; i++) {
        int row = m0 + ty * 4 + i;
        if (row < M) {
            float4 v = make_float4(acc[i][0], acc[i][1], acc[i][2], acc[i][3]);
            *reinterpret_cast<float4*>(C + (size_t)row * 256 + n0 + tx * 4) = v;
        }
    }
}

// ---------------- alpha1: as1/ad1[n,h] = sum_c h1[n,h,c]*att[h,c] ----------
__global__ __launch_bounds__(256) void alpha1_kernel(const float* __restrict__ h1,
                                                     const float* __restrict__ a_src,
                                                     const float* __restrict__ a_dst,
                                                     float* __restrict__ as1,
                                                     float* __restrict__ ad1) {
    int n = blockIdx.x;
    int t = threadIdx.x;
    float hv = h1[(size_t)n * 256 + t];
    float ps = hv * a_src[t];
    float pd = hv * a_dst[t];
    ps = wave_reduce_sum(ps);
    pd = wave_reduce_sum(pd);
    if ((t & 63) == 0) {
        as1[n * 4 + (t >> 6)] = ps;
        ad1[n * 4 + (t >> 6)] = pd;
    }
}

// ---------------- CSR build ----------------
__global__ void count_kernel(const int* __restrict__ ei, int* __restrict__ counts) {
    int idx = blockIdx.x * blockDim.x + threadIdx.x;
    if (idx >= ETOT) return;
    int d = (idx < NEDGES) ? ei[NEDGES + idx] : (idx - NEDGES);
    atomicAdd(&counts[d], 1);
}

__global__ void scan_kernel(const int* __restrict__ counts, int* __restrict__ rowptr, int n) {
    __shared__ int sh[1024];
    int tid = threadIdx.x;
    int carry = 0;
    for (int base = 0; base < n; base += 1024) {
        int i = base + tid;
        int v = (i < n) ? counts[i] : 0;
        sh[tid] = v;
        __syncthreads();
        for (int off = 1; off < 1024; off <<= 1) {
            int t = (tid >= off) ? sh[tid - off] : 0;
            __syncthreads();
            sh[tid] += t;
            __syncthreads();
        }
        int incl = sh[tid];
        int total = sh[1023];
        if (i < n) rowptr[i] = carry + incl - v;
        carry += total;
        __syncthreads();
    }
    if (tid == 0) rowptr[n] = carry;
}

__global__ void scatter_kernel(const int* __restrict__ ei, const int* __restrict__ rowptr,
                               int* __restrict__ cursor, int* __restrict__ col) {
    int idx = blockIdx.x * blockDim.x + threadIdx.x;
    if (idx >= ETOT) return;
    int s, d;
    if (idx < NEDGES) { s = ei[idx]; d = ei[NEDGES + idx]; }
    else { s = idx - NEDGES; d = s; }
    int pos = atomicAdd(&cursor[d], 1);
    col[rowptr[d] + pos] = s;
}

// ---------------- agg1: softmax-weighted aggregation + bias + ELU ----------
__global__ __launch_bounds__(256) void agg1_kernel(const float* __restrict__ h1,
                                                   const float* __restrict__ as1,
                                                   const float* __restrict__ ad1,
                                                   const int* __restrict__ rowptr,
                                                   const int* __restrict__ col,
                                                   const float* __restrict__ b1,
                                                   float* __restrict__ out1) {
    int n = blockIdx.x;
    int tid = threadIdx.x;
    int lane = tid & 63, wid = tid >> 6;
    int beg = rowptr[n], end = rowptr[n + 1];
    int deg = end - beg;

    __shared__ float m_sh[4], d_sh[4];
    __shared__ float red[4][4];
    __shared__ int src_sh[256];
    __shared__ float ex_sh[256][4];

    float adn[4];
    #pragma unroll
    for (int h = 0; h < 4; h++) adn[h] = ad1[n * 4 + h];

    float lm[4] = {-INFINITY, -INFINITY, -INFINITY, -INFINITY};
    for (int i = tid; i < deg; i += 256) {
        int s = col[beg + i];
        #pragma unroll
        for (int h = 0; h < 4; h++) {
            float el = as1[s * 4 + h] + adn[h];
            el = el > 0.f ? el : NEG_SLOPE * el;
            lm[h] = fmaxf(lm[h], el);
        }
    }
    #pragma unroll
    for (int h = 0; h < 4; h++) {
        float v = wave_reduce_max(lm[h]);
        if (lane == 0) red[wid][h] = v;
    }
    __syncthreads();
    if (tid < 4) {
        m_sh[tid] = fmaxf(fmaxf(red[0][tid], red[1][tid]), fmaxf(red[2][tid], red[3][tid]));
    }
    __syncthreads();
    float mh[4];
    #pragma unroll
    for (int h = 0; h < 4; h++) mh[h] = m_sh[h];

    float ls[4] = {0.f, 0.f, 0.f, 0.f};
    for (int i = tid; i < deg; i += 256) {
        int s = col[beg + i];
        #pragma unroll
        for (int h = 0; h < 4; h++) {
            float el = as1[s * 4 + h] + adn[h];
            el = el > 0.f ? el : NEG_SLOPE * el;
            ls[h] += expf(el - mh[h]);
        }
    }
    #pragma unroll
    for (int h = 0; h < 4; h++) {
        float v = wave_reduce_sum(ls[h]);
        if (lane == 0) red[wid][h] = v;
    }
    __syncthreads();
    if (tid < 4) d_sh[tid] = red[0][tid] + red[1][tid] + red[2][tid] + red[3][tid] + 1e-16f;
    __syncthreads();

    int h = tid >> 6;
    float dinv = 1.f / d_sh[h];
    float acc = 0.f;
    for (int c0 = 0; c0 < deg; c0 += 256) {
        int cn = min(256, deg - c0);
        if (tid < cn) {
            int s = col[beg + c0 + tid];
            src_sh[tid] = s;
            #pragma unroll
            for (int hh = 0; hh < 4; hh++) {
                float el = as1[s * 4 + hh] + adn[hh];
                el = el > 0.f ? el : NEG_SLOPE * el;
                ex_sh[tid][hh] = expf(el - mh[hh]);
            }
        }
        __syncthreads();
        for (int i = 0; i < cn; i++) {
            acc += h1[(size_t)src_sh[i] * 256 + tid] * ex_sh[i][h];
        }
        __syncthreads();
    }
    float o = acc * dinv + b1[tid];
    o = o > 0.f ? o : expm1f(o);
    out1[(size_t)n * 256 + tid] = o;
}

// ---------------- GEMM2: h2[M,40] = out1[M,256] @ W2[256,40] ----------------
__global__ __launch_bounds__(256) void gemm2_kernel(const float* __restrict__ X,
                                                    const float* __restrict__ W2,
                                                    float* __restrict__ h2, int M) {
    __shared__ float w_sh[256 * 40];
    int tid = threadIdx.x;
    for (int i = tid; i < 256 * 40; i += 256) w_sh[i] = W2[i];
    __syncthreads();
    int row0 = blockIdx.x * 64;
    for (int oi = tid; oi < 64 * 40; oi += 256) {
        int r = oi / 40, c = oi % 40;
        int row = row0 + r;
        if (row < M) {
            const float* xr = X + (size_t)row * 256;
            float acc = 0.f;
            #pragma unroll 8
            for (int k = 0; k < 256; k++) acc += xr[k] * w_sh[k * 40 + c];
            h2[(size_t)row * 40 + c] = acc;
        }
    }
}

// ---------------- alpha2 ----------------
__global__ __launch_bounds__(256) void alpha2_kernel(const float* __restrict__ h2,
                                                     const float* __restrict__ a_src,
                                                     const float* __restrict__ a_dst,
                                                     float* __restrict__ as2,
                                                     float* __restrict__ ad2) {
    int wid = threadIdx.x >> 6, lane = threadIdx.x & 63;
    int n = blockIdx.x * 4 + wid;
    float ps = 0.f, pd = 0.f;
    if (lane < OUT_DIM) {
        float hv = h2[(size_t)n * OUT_DIM + lane];
        ps = hv * a_src[lane];
        pd = hv * a_dst[lane];
    }
    ps = wave_reduce_sum(ps);
    pd = wave_reduce_sum(pd);
    if (lane == 0) { as2[n] = ps; ad2[n] = pd; }
}

// ---------------- agg2 + bias + log_softmax ----------------
__global__ __launch_bounds__(256) void agg2_kernel(const float* __restrict__ h2,
                                                   const float* __restrict__ as2,
                                                   const float* __restrict__ ad2,
                                                   const int* __restrict__ rowptr,
                                                   const int* __restrict__ col,
                                                   const float* __restrict__ b2,
                                                   float* __restrict__ out) {
    int wid = threadIdx.x >> 6, lane = threadIdx.x & 63;
    int n = blockIdx.x * 4 + wid;
    int beg = rowptr[n], end = rowptr[n + 1];
    int deg = end - beg;
    float adn = ad2[n];

    float lm = -INFINITY;
    for (int i = lane; i < deg; i += 64) {
        int s = col[beg + i];
        float el = as2[s] + adn;
        el = el > 0.f ? el : NEG_SLOPE * el;
        lm = fmaxf(lm, el);
    }
    float m = wave_reduce_max(lm);

    float lsum = 0.f;
    for (int i = lane; i < deg; i += 64) {
        int s = col[beg + i];
        float el = as2[s] + adn;
        el = el > 0.f ? el : NEG_SLOPE * el;
        lsum += expf(el - m);
    }
    float denom = wave_reduce_sum(lsum) + 1e-16f;

    float acc = 0.f;
    for (int c0 = 0; c0 < deg; c0 += 64) {
        int cn = min(64, deg - c0);
        int s_l = 0;
        float ex_l = 0.f;
        if (lane < cn) {
            s_l = col[beg + c0 + lane];
            float el = as2[s_l] + adn;
            el = el > 0.f ? el : NEG_SLOPE * el;
            ex_l = expf(el - m);
        }
        for (int i = 0; i < cn; i++) {
            int s = __shfl(s_l, i);
            float w = __shfl(ex_l, i);
            if (lane < OUT_DIM) acc += h2[(size_t)s * OUT_DIM + lane] * w;
        }
    }

    float v = (lane < OUT_DIM) ? (acc / denom + b2[lane]) : -INFINITY;
    float mx = wave_reduce_max(v);
    float ev = (lane < OUT_DIM) ? expf(v - mx) : 0.f;
    float ssum = wave_reduce_sum(ev);
    if (lane < OUT_DIM) out[(size_t)n * OUT_DIM + lane] = v - mx - logf(ssum);
}

// ---------------- launch ----------------
extern "C" void kernel_launch(void* const* d_in, const int* in_sizes, int n_in,
                              void* d_out, int out_size, void* d_ws, size_t ws_size,
                              hipStream_t stream) {
    const float* x        = (const float*)d_in[0];
    const int*   ei       = (const int*)d_in[1];
    const float* W1       = (const float*)d_in[2];
    const float* att_src1 = (const float*)d_in[3];
    const float* att_dst1 = (const float*)d_in[4];
    const float* b1       = (const float*)d_in[5];
    const float* W2       = (const float*)d_in[6];
    const float* att_src2 = (const float*)d_in[7];
    const float* att_dst2 = (const float*)d_in[8];
    const float* b2       = (const float*)d_in[9];
    float* out = (float*)d_out;

    char* ws = (char*)d_ws;
    auto alloc = [&](size_t bytes) {
        char* p = ws;
        ws += (bytes + 255) & ~(size_t)255;
        return p;
    };
    float* h1     = (float*)alloc((size_t)NNODES * 256 * 4);
    float* out1   = (float*)alloc((size_t)NNODES * 256 * 4);
    float* h2     = (float*)alloc((size_t)NNODES * OUT_DIM * 4);
    float* as1    = (float*)alloc((size_t)NNODES * 4 * 4);
    float* ad1    = (float*)alloc((size_t)NNODES * 4 * 4);
    float* as2    = (float*)alloc((size_t)NNODES * 4);
    float* ad2    = (float*)alloc((size_t)NNODES * 4);
    int*   counts = (int*)alloc((size_t)2 * NNODES * 4);  // counts + cursor adjacent
    int*   cursor = counts + NNODES;
    int*   rowptr = (int*)alloc((size_t)(NNODES + 1) * 4);
    int*   col    = (int*)alloc((size_t)ETOT * 4);
    if ((size_t)(ws - (char*)d_ws) > ws_size) return;  // workspace too small

    hipMemsetAsync(counts, 0, (size_t)2 * NNODES * 4, stream);

    dim3 g1(256 / 64, (NNODES + 63) / 64);
    gemm1_kernel<<<g1, 256, 0, stream>>>(x, W1, h1, NNODES);
    alpha1_kernel<<<NNODES, 256, 0, stream>>>(h1, att_src1, att_dst1, as1, ad1);

    int eb = (ETOT + 255) / 256;
    count_kernel<<<eb, 256, 0, stream>>>(ei, counts);
    scan_kernel<<<1, 1024, 0, stream>>>(counts, rowptr, NNODES);
    scatter_kernel<<<eb, 256, 0, stream>>>(ei, rowptr, cursor, col);

    agg1_kernel<<<NNODES, 256, 0, stream>>>(h1, as1, ad1, rowptr, col, b1, out1);

    gemm2_kernel<<<(NNODES + 63) / 64, 256, 0, stream>>>(out1, W2, h2, NNODES);
    alpha2_kernel<<<NNODES / 4, 256, 0, stream>>>(h2, att_src2, att_dst2, as2, ad2);
    agg2_kernel<<<NNODES / 4, 256, 0, stream>>>(h2, as2, ad2, rowptr, col, b2, out);
}

// Round 2
// 472.523 us; speedup vs baseline: 1.3522x; 1.3522x over previous
//
#include <hip/hip_runtime.h>
#include <hip/hip_bf16.h>
#include <math.h>

#define NNODES 50000
#define M_PAD  50048   // 391 * 128
#define IN_DIM 256
#define HID 64
#define HEADS 4
#define OUT_DIM 40
#define NEDGES 800000
#define ETOT (NEDGES + NNODES)
#define NEG_SLOPE 0.2f
#define NB_SCAN 196    // ceil(50000/256)

typedef __attribute__((ext_vector_type(8))) short bf16x8;
typedef __attribute__((ext_vector_type(4))) float f32x4;

__device__ __forceinline__ ushort f2bf(float f) {
    uint u = __float_as_uint(f);
    u += 0x7FFF + ((u >> 16) & 1);
    return (ushort)(u >> 16);
}
__device__ __forceinline__ float bf2f(ushort u) {
    return __uint_as_float(((uint)u) << 16);
}
__device__ __forceinline__ float wave_reduce_max(float v) {
    #pragma unroll
    for (int off = 32; off > 0; off >>= 1) v = fmaxf(v, __shfl_xor(v, off));
    return v;
}
__device__ __forceinline__ float wave_reduce_sum(float v) {
    #pragma unroll
    for (int off = 32; off > 0; off >>= 1) v += __shfl_xor(v, off);
    return v;
}

// ---------------- convert x -> bf16 ----------------
__global__ __launch_bounds__(256) void cvt_x_kernel(const float* __restrict__ x,
                                                    ushort* __restrict__ xb) {
    size_t i = ((size_t)blockIdx.x * 256 + threadIdx.x) * 8;
    float4 a = *reinterpret_cast<const float4*>(x + i);
    float4 b = *reinterpret_cast<const float4*>(x + i + 4);
    uint4 o;
    o.x = (uint)f2bf(a.x) | ((uint)f2bf(a.y) << 16);
    o.y = (uint)f2bf(a.z) | ((uint)f2bf(a.w) << 16);
    o.z = (uint)f2bf(b.x) | ((uint)f2bf(b.y) << 16);
    o.w = (uint)f2bf(b.z) | ((uint)f2bf(b.w) << 16);
    *reinterpret_cast<uint4*>(xb + i) = o;
}

// ---------------- W1t[n][k] = bf16(W1[k][n]) ----------------
__global__ __launch_bounds__(256) void cvt_w1t_kernel(const float* __restrict__ W1,
                                                      ushort* __restrict__ W1t) {
    int n = blockIdx.x, k = threadIdx.x;
    W1t[n * 256 + k] = f2bf(W1[k * 256 + n]);
}

// ---------------- GEMM1 (MFMA bf16): h1b[M_PAD,256] = xb @ W1 ----------------
// A = xb [M_PAD][256] bf16 row-major; B^T = W1t [256n][256k] bf16.
__global__ __launch_bounds__(256) void gemm1_mfma(const ushort* __restrict__ Ag,
                                                  const ushort* __restrict__ Btg,
                                                  ushort* __restrict__ Cg) {
    __shared__ ushort As[128 * 32];
    __shared__ ushort Bs[128 * 32];
    int t = threadIdx.x;
    int l = t & 63, wid = t >> 6;
    int wm = wid & 1, wn = wid >> 1;
    int m0 = blockIdx.y * 128, n0 = blockIdx.x * 128;

    int srow = t >> 2;      // 0..63
    int skb = t & 3;        // 16B chunk within 64B row

    f32x4 acc[4][4];
    #pragma unroll
    for (int i = 0; i < 4; i++)
        #pragma unroll
        for (int j = 0; j < 4; j++) acc[i][j] = (f32x4){0.f, 0.f, 0.f, 0.f};

    int lrow = l & 15, lks = l >> 4;
    int swzf = (lrow >> 1) & 3;
    int ks = lks ^ swzf;

    for (int k0 = 0; k0 < 256; k0 += 32) {
        #pragma unroll
        for (int c = 0; c < 2; ++c) {
            int row = srow + c * 64;
            int slot = skb ^ ((row >> 1) & 3);
            uint4 av = *reinterpret_cast<const uint4*>(Ag + (size_t)(m0 + row) * 256 + k0 + skb * 8);
            *reinterpret_cast<uint4*>(&As[row * 32 + slot * 8]) = av;
            uint4 bv = *reinterpret_cast<const uint4*>(Btg + (size_t)(n0 + row) * 256 + k0 + skb * 8);
            *reinterpret_cast<uint4*>(&Bs[row * 32 + slot * 8]) = bv;
        }
        __syncthreads();
        bf16x8 a_frag[4], b_frag[4];
        #pragma unroll
        for (int mf = 0; mf < 4; mf++)
            a_frag[mf] = *reinterpret_cast<const bf16x8*>(&As[(wm * 64 + mf * 16 + lrow) * 32 + ks * 8]);
        #pragma unroll
        for (int nf = 0; nf < 4; nf++)
            b_frag[nf] = *reinterpret_cast<const bf16x8*>(&Bs[(wn * 64 + nf * 16 + lrow) * 32 + ks * 8]);
        #pragma unroll
        for (int mf = 0; mf < 4; mf++)
            #pragma unroll
            for (int nf = 0; nf < 4; nf++)
                acc[mf][nf] = __builtin_amdgcn_mfma_f32_16x16x32_bf16(a_frag[mf], b_frag[nf], acc[mf][nf], 0, 0, 0);
        __syncthreads();
    }

    #pragma unroll
    for (int mf = 0; mf < 4; mf++)
        #pragma unroll
        for (int nf = 0; nf < 4; nf++) {
            int col = n0 + wn * 64 + nf * 16 + lrow;
            #pragma unroll
            for (int r = 0; r < 4; r++) {
                int row = m0 + wm * 64 + mf * 16 + lks * 4 + r;
                Cg[(size_t)row * 256 + col] = f2bf(acc[mf][nf][r]);
            }
        }
}

// ---------------- alpha1 from bf16 h1 ----------------
__global__ __launch_bounds__(256) void alpha1_kernel(const ushort* __restrict__ h1b,
                                                     const float* __restrict__ a_src,
                                                     const float* __restrict__ a_dst,
                                                     float* __restrict__ as1,
                                                     float* __restrict__ ad1) {
    int n = blockIdx.x;
    int t = threadIdx.x;
    float hv = bf2f(h1b[(size_t)n * 256 + t]);
    float ps = hv * a_src[t];
    float pd = hv * a_dst[t];
    ps = wave_reduce_sum(ps);
    pd = wave_reduce_sum(pd);
    if ((t & 63) == 0) {
        as1[n * 4 + (t >> 6)] = ps;
        ad1[n * 4 + (t >> 6)] = pd;
    }
}

// ---------------- CSR build ----------------
__global__ void count_kernel(const int* __restrict__ ei, int* __restrict__ counts) {
    int idx = blockIdx.x * blockDim.x + threadIdx.x;
    if (idx >= ETOT) return;
    int d = (idx < NEDGES) ? ei[NEDGES + idx] : (idx - NEDGES);
    atomicAdd(&counts[d], 1);
}

__global__ __launch_bounds__(256) void scanA_kernel(const int* __restrict__ counts,
                                                    int* __restrict__ rowptr,
                                                    int* __restrict__ bsum) {
    __shared__ int sh[256];
    int t = threadIdx.x;
    int i = blockIdx.x * 256 + t;
    int v = (i < NNODES) ? counts[i] : 0;
    int x = v;
    sh[t] = x;
    __syncthreads();
    #pragma unroll
    for (int off = 1; off < 256; off <<= 1) {
        int y = (t >= off) ? sh[t - off] : 0;
        __syncthreads();
        x += y;
        sh[t] = x;
        __syncthreads();
    }
    if (i < NNODES) rowptr[i] = x - v;  // exclusive within block
    if (t == 255) bsum[blockIdx.x] = x;
}

__global__ __launch_bounds__(256) void scanB_kernel(int* __restrict__ bsum,
                                                    int* __restrict__ bsum_e) {
    __shared__ int sh[256];
    int t = threadIdx.x;
    int v = (t < NB_SCAN) ? bsum[t] : 0;
    int x = v;
    sh[t] = x;
    __syncthreads();
    #pragma unroll
    for (int off = 1; off < 256; off <<= 1) {
        int y = (t >= off) ? sh[t - off] : 0;
        __syncthreads();
        x += y;
        sh[t] = x;
        __syncthreads();
    }
    if (t < NB_SCAN) bsum_e[t] = x - v;
}

__global__ __launch_bounds__(256) void scanC_kernel(int* __restrict__ rowptr,
                                                    const int* __restrict__ bsum_e) {
    int i = blockIdx.x * 256 + threadIdx.x;
    if (i < NNODES) rowptr[i] += bsum_e[i >> 8];
    if (i == 0) rowptr[NNODES] = ETOT;
}

__global__ void scatter_kernel(const int* __restrict__ ei, const int* __restrict__ rowptr,
                               int* __restrict__ cursor, int* __restrict__ col) {
    int idx = blockIdx.x * blockDim.x + threadIdx.x;
    if (idx >= ETOT) return;
    int s, d;
    if (idx < NEDGES) { s = ei[idx]; d = ei[NEDGES + idx]; }
    else { s = idx - NEDGES; d = s; }
    int pos = atomicAdd(&cursor[d], 1);
    col[rowptr[d] + pos] = s;
}

// ---------------- agg1: softmax aggregation + bias + ELU -> bf16 ----------
__global__ __launch_bounds__(256) void agg1_kernel(const ushort* __restrict__ h1b,
                                                   const float* __restrict__ as1,
                                                   const float* __restrict__ ad1,
                                                   const int* __restrict__ rowptr,
                                                   const int* __restrict__ col,
                                                   const float* __restrict__ b1,
                                                   ushort* __restrict__ out1b) {
    int n = blockIdx.x;
    int tid = threadIdx.x;
    int lane = tid & 63, wid = tid >> 6;
    int beg = rowptr[n], end = rowptr[n + 1];
    int deg = end - beg;

    __shared__ float m_sh[4];
    __shared__ float red[4][4];
    __shared__ int src_sh[256];
    __shared__ float ex_sh[256][4];

    float adn[4];
    {
        float4 a4 = *reinterpret_cast<const float4*>(&ad1[n * 4]);
        adn[0] = a4.x; adn[1] = a4.y; adn[2] = a4.z; adn[3] = a4.w;
    }

    // pass 1: max per head
    float lm[4] = {-INFINITY, -INFINITY, -INFINITY, -INFINITY};
    for (int i = tid; i < deg; i += 256) {
        int s = col[beg + i];
        float4 a4 = *reinterpret_cast<const float4*>(&as1[s * 4]);
        float e0 = a4.x + adn[0], e1 = a4.y + adn[1], e2 = a4.z + adn[2], e3 = a4.w + adn[3];
        e0 = e0 > 0.f ? e0 : NEG_SLOPE * e0;
        e1 = e1 > 0.f ? e1 : NEG_SLOPE * e1;
        e2 = e2 > 0.f ? e2 : NEG_SLOPE * e2;
        e3 = e3 > 0.f ? e3 : NEG_SLOPE * e3;
        lm[0] = fmaxf(lm[0], e0); lm[1] = fmaxf(lm[1], e1);
        lm[2] = fmaxf(lm[2], e2); lm[3] = fmaxf(lm[3], e3);
    }
    #pragma unroll
    for (int h = 0; h < 4; h++) {
        float v = wave_reduce_max(lm[h]);
        if (lane == 0) red[wid][h] = v;
    }
    __syncthreads();
    if (tid < 4)
        m_sh[tid] = fmaxf(fmaxf(red[0][tid], red[1][tid]), fmaxf(red[2][tid], red[3][tid]));
    __syncthreads();
    float mh[4];
    #pragma unroll
    for (int h = 0; h < 4; h++) mh[h] = m_sh[h];

    // chunked: ex -> LDS, accumulate denom + weighted gather
    int h = tid >> 6;
    float ls = 0.f;
    float acc = 0.f;
    for (int c0 = 0; c0 < deg; c0 += 256) {
        int cn = min(256, deg - c0);
        if (tid < cn) {
            int s = col[beg + c0 + tid];
            src_sh[tid] = s;
            float4 a4 = *reinterpret_cast<const float4*>(&as1[s * 4]);
            float e0 = a4.x + adn[0], e1 = a4.y + adn[1], e2 = a4.z + adn[2], e3 = a4.w + adn[3];
            e0 = e0 > 0.f ? e0 : NEG_SLOPE * e0;
            e1 = e1 > 0.f ? e1 : NEG_SLOPE * e1;
            e2 = e2 > 0.f ? e2 : NEG_SLOPE * e2;
            e3 = e3 > 0.f ? e3 : NEG_SLOPE * e3;
            ex_sh[tid][0] = __expf(e0 - mh[0]);
            ex_sh[tid][1] = __expf(e1 - mh[1]);
            ex_sh[tid][2] = __expf(e2 - mh[2]);
            ex_sh[tid][3] = __expf(e3 - mh[3]);
        }
        __syncthreads();
        for (int i = 0; i < cn; i++) {
            float w = ex_sh[i][h];
            ls += w;
            acc += bf2f(h1b[(size_t)src_sh[i] * 256 + tid]) * w;
        }
        __syncthreads();
    }
    float o = acc / (ls + 1e-16f) + b1[tid];
    o = o > 0.f ? o : expm1f(o);
    out1b[(size_t)n * 256 + tid] = f2bf(o);
}

// ---------------- GEMM2: h2[M,40] = out1b[M,256] @ W2[256,40] --------------
__global__ __launch_bounds__(256) void gemm2_kernel(const ushort* __restrict__ X,
                                                    const float* __restrict__ W2,
                                                    float* __restrict__ h2, int M) {
    __shared__ float w_sh[256 * 40];
    int tid = threadIdx.x;
    for (int i = tid; i < 256 * 40; i += 256) w_sh[i] = W2[i];
    __syncthreads();
    int row0 = blockIdx.x * 64;
    for (int oi = tid; oi < 64 * 40; oi += 256) {
        int r = oi / 40, c = oi % 40;
        int row = row0 + r;
        if (row < M) {
            const ushort* xr = X + (size_t)row * 256;
            float acc = 0.f;
            #pragma unroll 8
            for (int k = 0; k < 256; k++) acc += bf2f(xr[k]) * w_sh[k * 40 + c];
            h2[(size_t)row * 40 + c] = acc;
        }
    }
}

// ---------------- alpha2 ----------------
__global__ __launch_bounds__(256) void alpha2_kernel(const float* __restrict__ h2,
                                                     const float* __restrict__ a_src,
                                                     const float* __restrict__ a_dst,
                                                     float* __restrict__ as2,
                                                     float* __restrict__ ad2) {
    int wid = threadIdx.x >> 6, lane = threadIdx.x & 63;
    int n = blockIdx.x * 4 + wid;
    float ps = 0.f, pd = 0.f;
    if (lane < OUT_DIM) {
        float hv = h2[(size_t)n * OUT_DIM + lane];
        ps = hv * a_src[lane];
        pd = hv * a_dst[lane];
    }
    ps = wave_reduce_sum(ps);
    pd = wave_reduce_sum(pd);
    if (lane == 0) { as2[n] = ps; ad2[n] = pd; }
}

// ---------------- agg2 + bias + log_softmax ----------------
__global__ __launch_bounds__(256) void agg2_kernel(const float* __restrict__ h2,
                                                   const float* __restrict__ as2,
                                                   const float* __restrict__ ad2,
                                                   const int* __restrict__ rowptr,
                                                   const int* __restrict__ col,
                                                   const float* __restrict__ b2,
                                                   float* __restrict__ out) {
    int wid = threadIdx.x >> 6, lane = threadIdx.x & 63;
    int n = blockIdx.x * 4 + wid;
    int beg = rowptr[n], end = rowptr[n + 1];
    int deg = end - beg;
    float adn = ad2[n];

    float lm = -INFINITY;
    for (int i = lane; i < deg; i += 64) {
        int s = col[beg + i];
        float el = as2[s] + adn;
        el = el > 0.f ? el : NEG_SLOPE * el;
        lm = fmaxf(lm, el);
    }
    float m = wave_reduce_max(lm);

    float lsum = 0.f;
    for (int i = lane; i < deg; i += 64) {
        int s = col[beg + i];
        float el = as2[s] + adn;
        el = el > 0.f ? el : NEG_SLOPE * el;
        lsum += __expf(el - m);
    }
    float denom = wave_reduce_sum(lsum) + 1e-16f;

    float acc = 0.f;
    for (int c0 = 0; c0 < deg; c0 += 64) {
        int cn = min(64, deg - c0);
        int s_l = 0;
        float ex_l = 0.f;
        if (lane < cn) {
            s_l = col[beg + c0 + lane];
            float el = as2[s_l] + adn;
            el = el > 0.f ? el : NEG_SLOPE * el;
            ex_l = __expf(el - m);
        }
        for (int i = 0; i < cn; i++) {
            int s = __shfl(s_l, i);
            float w = __shfl(ex_l, i);
            if (lane < OUT_DIM) acc += h2[(size_t)s * OUT_DIM + lane] * w;
        }
    }

    float v = (lane < OUT_DIM) ? (acc / denom + b2[lane]) : -INFINITY;
    float mx = wave_reduce_max(v);
    float ev = (lane < OUT_DIM) ? __expf(v - mx) : 0.f;
    float ssum = wave_reduce_sum(ev);
    if (lane < OUT_DIM) out[(size_t)n * OUT_DIM + lane] = v - mx - logf(ssum);
}

// ---------------- launch ----------------
extern "C" void kernel_launch(void* const* d_in, const int* in_sizes, int n_in,
                              void* d_out, int out_size, void* d_ws, size_t ws_size,
                              hipStream_t stream) {
    const float* x        = (const float*)d_in[0];
    const int*   ei       = (const int*)d_in[1];
    const float* W1       = (const float*)d_in[2];
    const float* att_src1 = (const float*)d_in[3];
    const float* att_dst1 = (const float*)d_in[4];
    const float* b1       = (const float*)d_in[5];
    const float* W2       = (const float*)d_in[6];
    const float* att_src2 = (const float*)d_in[7];
    const float* att_dst2 = (const float*)d_in[8];
    const float* b2       = (const float*)d_in[9];
    float* out = (float*)d_out;

    char* ws = (char*)d_ws;
    auto alloc = [&](size_t bytes) {
        char* p = ws;
        ws += (bytes + 255) & ~(size_t)255;
        return p;
    };
    ushort* xb     = (ushort*)alloc((size_t)M_PAD * 256 * 2);
    ushort* h1b    = (ushort*)alloc((size_t)M_PAD * 256 * 2);
    ushort* W1t    = (ushort*)alloc((size_t)256 * 256 * 2);
    ushort* out1b  = (ushort*)alloc((size_t)NNODES * 256 * 2);
    float*  h2     = (float*)alloc((size_t)NNODES * OUT_DIM * 4);
    float*  as1    = (float*)alloc((size_t)NNODES * 4 * 4);
    float*  ad1    = (float*)alloc((size_t)NNODES * 4 * 4);
    float*  as2    = (float*)alloc((size_t)NNODES * 4);
    float*  ad2    = (float*)alloc((size_t)NNODES * 4);
    int*    counts = (int*)alloc((size_t)2 * NNODES * 4);  // counts + cursor
    int*    cursor = counts + NNODES;
    int*    rowptr = (int*)alloc((size_t)(NNODES + 1) * 4);
    int*    col    = (int*)alloc((size_t)ETOT * 4);
    int*    bsum   = (int*)alloc((size_t)2 * 256 * 4);
    int*    bsum_e = bsum + 256;
    if ((size_t)(ws - (char*)d_ws) > ws_size) return;

    hipMemsetAsync(counts, 0, (size_t)2 * NNODES * 4, stream);

    cvt_x_kernel<<<(NNODES * 256) / 2048, 256, 0, stream>>>(x, xb);
    cvt_w1t_kernel<<<256, 256, 0, stream>>>(W1, W1t);

    dim3 g1(2, M_PAD / 128);
    gemm1_mfma<<<g1, 256, 0, stream>>>(xb, W1t, h1b);
    alpha1_kernel<<<NNODES, 256, 0, stream>>>(h1b, att_src1, att_dst1, as1, ad1);

    int eb = (ETOT + 255) / 256;
    count_kernel<<<eb, 256, 0, stream>>>(ei, counts);
    scanA_kernel<<<NB_SCAN, 256, 0, stream>>>(counts, rowptr, bsum);
    scanB_kernel<<<1, 256, 0, stream>>>(bsum, bsum_e);
    scanC_kernel<<<NB_SCAN, 256, 0, stream>>>(rowptr, bsum_e);
    scatter_kernel<<<eb, 256, 0, stream>>>(ei, rowptr, cursor, col);

    agg1_kernel<<<NNODES, 256, 0, stream>>>(h1b, as1, ad1, rowptr, col, b1, out1b);

    gemm2_kernel<<<(NNODES + 63) / 64, 256, 0, stream>>>(out1b, W2, h2, NNODES);
    alpha2_kernel<<<NNODES / 4, 256, 0, stream>>>(h2, att_src2, att_dst2, as2, ad2);
    agg2_kernel<<<NNODES / 4, 256, 0, stream>>>(h2, as2, ad2, rowptr, col, b2, out);
}

// Round 3
// 381.436 us; speedup vs baseline: 1.6751x; 1.2388x over previous
//
#include <hip/hip_runtime.h>
#include <hip/hip_bf16.h>
#include <math.h>

#define NNODES 50000
#define M_PAD  50048   // 391 * 128
#define IN_DIM 256
#define HID 64
#define HEADS 4
#define OUT_DIM 40
#define NEDGES 800000
#define ETOT (NEDGES + NNODES)
#define NEG_SLOPE 0.2f
#define NB_SCAN 196    // ceil(50000/256)

typedef __attribute__((ext_vector_type(8))) short bf16x8;
typedef __attribute__((ext_vector_type(4))) float f32x4;

__device__ __forceinline__ ushort f2bf(float f) {
    uint u = __float_as_uint(f);
    u += 0x7FFF + ((u >> 16) & 1);
    return (ushort)(u >> 16);
}
__device__ __forceinline__ float bf2f(ushort u) {
    return __uint_as_float(((uint)u) << 16);
}
__device__ __forceinline__ uint fkey(float f) {   // order-preserving float->uint
    uint u = __float_as_uint(f);
    return (u & 0x80000000u) ? ~u : (u | 0x80000000u);
}
__device__ __forceinline__ float fdec(uint k) {
    return (k & 0x80000000u) ? __uint_as_float(k & 0x7fffffffu) : __uint_as_float(~k);
}
__device__ __forceinline__ float wave_reduce_max(float v) {
    #pragma unroll
    for (int off = 32; off > 0; off >>= 1) v = fmaxf(v, __shfl_xor(v, off));
    return v;
}
__device__ __forceinline__ float wave_reduce_sum(float v) {
    #pragma unroll
    for (int off = 32; off > 0; off >>= 1) v += __shfl_xor(v, off);
    return v;
}

// ---------------- convert x -> bf16 ----------------
__global__ __launch_bounds__(256) void cvt_x_kernel(const float* __restrict__ x,
                                                    ushort* __restrict__ xb) {
    size_t i = ((size_t)blockIdx.x * 256 + threadIdx.x) * 8;
    float4 a = *reinterpret_cast<const float4*>(x + i);
    float4 b = *reinterpret_cast<const float4*>(x + i + 4);
    uint4 o;
    o.x = (uint)f2bf(a.x) | ((uint)f2bf(a.y) << 16);
    o.y = (uint)f2bf(a.z) | ((uint)f2bf(a.w) << 16);
    o.z = (uint)f2bf(b.x) | ((uint)f2bf(b.y) << 16);
    o.w = (uint)f2bf(b.z) | ((uint)f2bf(b.w) << 16);
    *reinterpret_cast<uint4*>(xb + i) = o;
}

// ---------------- W1t[n][k] = bf16(W1[k][n]) ----------------
__global__ __launch_bounds__(256) void cvt_w1t_kernel(const float* __restrict__ W1,
                                                      ushort* __restrict__ W1t) {
    int n = blockIdx.x, k = threadIdx.x;
    W1t[n * 256 + k] = f2bf(W1[k * 256 + n]);
}

// ---------------- W2tb[n][k] bf16, [48][264] padded ----------------
__global__ __launch_bounds__(256) void cvt_w2t_kernel(const float* __restrict__ W2,
                                                      ushort* __restrict__ W2tb) {
    int idx = blockIdx.x * 256 + threadIdx.x;
    if (idx >= 48 * 264) return;
    int n = idx / 264, k = idx % 264;
    W2tb[idx] = (n < OUT_DIM && k < 256) ? f2bf(W2[k * OUT_DIM + n]) : (ushort)0;
}

// ---------------- GEMM1 (MFMA bf16): h1b[M_PAD,256] = xb @ W1 ----------------
__global__ __launch_bounds__(256) void gemm1_mfma(const ushort* __restrict__ Ag,
                                                  const ushort* __restrict__ Btg,
                                                  ushort* __restrict__ Cg) {
    __shared__ ushort As[128 * 32];
    __shared__ ushort Bs[128 * 32];
    int t = threadIdx.x;
    int l = t & 63, wid = t >> 6;
    int wm = wid & 1, wn = wid >> 1;
    int m0 = blockIdx.y * 128, n0 = blockIdx.x * 128;

    int srow = t >> 2;      // 0..63
    int skb = t & 3;        // 16B chunk within 64B row

    f32x4 acc[4][4];
    #pragma unroll
    for (int i = 0; i < 4; i++)
        #pragma unroll
        for (int j = 0; j < 4; j++) acc[i][j] = (f32x4){0.f, 0.f, 0.f, 0.f};

    int lrow = l & 15, lks = l >> 4;
    int swzf = (lrow >> 1) & 3;
    int ks = lks ^ swzf;

    for (int k0 = 0; k0 < 256; k0 += 32) {
        #pragma unroll
        for (int c = 0; c < 2; ++c) {
            int row = srow + c * 64;
            int slot = skb ^ ((row >> 1) & 3);
            uint4 av = *reinterpret_cast<const uint4*>(Ag + (size_t)(m0 + row) * 256 + k0 + skb * 8);
            *reinterpret_cast<uint4*>(&As[row * 32 + slot * 8]) = av;
            uint4 bv = *reinterpret_cast<const uint4*>(Btg + (size_t)(n0 + row) * 256 + k0 + skb * 8);
            *reinterpret_cast<uint4*>(&Bs[row * 32 + slot * 8]) = bv;
        }
        __syncthreads();
        bf16x8 a_frag[4], b_frag[4];
        #pragma unroll
        for (int mf = 0; mf < 4; mf++)
            a_frag[mf] = *reinterpret_cast<const bf16x8*>(&As[(wm * 64 + mf * 16 + lrow) * 32 + ks * 8]);
        #pragma unroll
        for (int nf = 0; nf < 4; nf++)
            b_frag[nf] = *reinterpret_cast<const bf16x8*>(&Bs[(wn * 64 + nf * 16 + lrow) * 32 + ks * 8]);
        #pragma unroll
        for (int mf = 0; mf < 4; mf++)
            #pragma unroll
            for (int nf = 0; nf < 4; nf++)
                acc[mf][nf] = __builtin_amdgcn_mfma_f32_16x16x32_bf16(a_frag[mf], b_frag[nf], acc[mf][nf], 0, 0, 0);
        __syncthreads();
    }

    #pragma unroll
    for (int mf = 0; mf < 4; mf++)
        #pragma unroll
        for (int nf = 0; nf < 4; nf++) {
            int col = n0 + wn * 64 + nf * 16 + lrow;
            #pragma unroll
            for (int r = 0; r < 4; r++) {
                int row = m0 + wm * 64 + mf * 16 + lks * 4 + r;
                Cg[(size_t)row * 256 + col] = f2bf(acc[mf][nf][r]);
            }
        }
}

// ---------------- alpha1 from bf16 h1 ----------------
__global__ __launch_bounds__(256) void alpha1_kernel(const ushort* __restrict__ h1b,
                                                     const float* __restrict__ a_src,
                                                     const float* __restrict__ a_dst,
                                                     float* __restrict__ as1,
                                                     float* __restrict__ ad1) {
    int n = blockIdx.x;
    int t = threadIdx.x;
    float hv = bf2f(h1b[(size_t)n * 256 + t]);
    float ps = hv * a_src[t];
    float pd = hv * a_dst[t];
    ps = wave_reduce_sum(ps);
    pd = wave_reduce_sum(pd);
    if ((t & 63) == 0) {
        as1[n * 4 + (t >> 6)] = ps;
        ad1[n * 4 + (t >> 6)] = pd;
    }
}

// ---------------- global max of as1 per head ----------------
__global__ __launch_bounds__(256) void gmax1_kernel(const float* __restrict__ as1,
                                                    uint* __restrict__ gb) {
    int i = blockIdx.x * 256 + threadIdx.x;
    int lane = threadIdx.x & 63;
    float4 v = make_float4(-INFINITY, -INFINITY, -INFINITY, -INFINITY);
    if (i < NNODES) v = *reinterpret_cast<const float4*>(&as1[i * 4]);
    v.x = wave_reduce_max(v.x);
    v.y = wave_reduce_max(v.y);
    v.z = wave_reduce_max(v.z);
    v.w = wave_reduce_max(v.w);
    if (lane == 0) {
        atomicMax(&gb[0], fkey(v.x));
        atomicMax(&gb[1], fkey(v.y));
        atomicMax(&gb[2], fkey(v.z));
        atomicMax(&gb[3], fkey(v.w));
    }
}

// ---------------- global max of as2 ----------------
__global__ __launch_bounds__(256) void gmax2_kernel(const float* __restrict__ as2,
                                                    uint* __restrict__ gb) {
    int i = blockIdx.x * 256 + threadIdx.x;
    int lane = threadIdx.x & 63;
    float v = (i < NNODES) ? as2[i] : -INFINITY;
    v = wave_reduce_max(v);
    if (lane == 0) atomicMax(&gb[4], fkey(v));
}

// ---------------- CSR build ----------------
__global__ void count_kernel(const int* __restrict__ ei, int* __restrict__ counts) {
    int idx = blockIdx.x * blockDim.x + threadIdx.x;
    if (idx >= ETOT) return;
    int d = (idx < NEDGES) ? ei[NEDGES + idx] : (idx - NEDGES);
    atomicAdd(&counts[d], 1);
}

__global__ __launch_bounds__(256) void scanA_kernel(const int* __restrict__ counts,
                                                    int* __restrict__ rowptr,
                                                    int* __restrict__ bsum) {
    __shared__ int sh[256];
    int t = threadIdx.x;
    int i = blockIdx.x * 256 + t;
    int v = (i < NNODES) ? counts[i] : 0;
    int x = v;
    sh[t] = x;
    __syncthreads();
    #pragma unroll
    for (int off = 1; off < 256; off <<= 1) {
        int y = (t >= off) ? sh[t - off] : 0;
        __syncthreads();
        x += y;
        sh[t] = x;
        __syncthreads();
    }
    if (i < NNODES) rowptr[i] = x - v;
    if (t == 255) bsum[blockIdx.x] = x;
}

__global__ __launch_bounds__(256) void scanB_kernel(int* __restrict__ bsum,
                                                    int* __restrict__ bsum_e) {
    __shared__ int sh[256];
    int t = threadIdx.x;
    int v = (t < NB_SCAN) ? bsum[t] : 0;
    int x = v;
    sh[t] = x;
    __syncthreads();
    #pragma unroll
    for (int off = 1; off < 256; off <<= 1) {
        int y = (t >= off) ? sh[t - off] : 0;
        __syncthreads();
        x += y;
        sh[t] = x;
        __syncthreads();
    }
    if (t < NB_SCAN) bsum_e[t] = x - v;
}

__global__ __launch_bounds__(256) void scanC_kernel(int* __restrict__ rowptr,
                                                    const int* __restrict__ bsum_e) {
    int i = blockIdx.x * 256 + threadIdx.x;
    if (i < NNODES) rowptr[i] += bsum_e[i >> 8];
    if (i == 0) rowptr[NNODES] = ETOT;
}

__global__ void scatter_kernel(const int* __restrict__ ei, const int* __restrict__ rowptr,
                               int* __restrict__ cursor, int* __restrict__ col) {
    int idx = blockIdx.x * blockDim.x + threadIdx.x;
    if (idx >= ETOT) return;
    int s, d;
    if (idx < NEDGES) { s = ei[idx]; d = ei[NEDGES + idx]; }
    else { s = idx - NEDGES; d = s; }
    int pos = atomicAdd(&cursor[d], 1);
    col[rowptr[d] + pos] = s;
}

// ---------------- agg1: single-pass softmax aggregation + bias + ELU -> bf16
// block = 1 node, 4 waves; each half-wave owns 1 neighbor (8 in flight),
// lane j<32 loads 16B (8 channels) of the neighbor's h1 row.
__global__ __launch_bounds__(256) void agg1_kernel(const ushort* __restrict__ h1b,
                                                   const float* __restrict__ as1,
                                                   const float* __restrict__ ad1,
                                                   const int* __restrict__ rowptr,
                                                   const int* __restrict__ col,
                                                   const float* __restrict__ b1,
                                                   const uint* __restrict__ gb,
                                                   ushort* __restrict__ out1b) {
    int n = blockIdx.x;
    int tid = threadIdx.x;
    int lane = tid & 63, wid = tid >> 6;
    int j = lane & 31, half = lane >> 5;
    int beg = rowptr[n], end = rowptr[n + 1];
    int deg = end - beg;

    __shared__ float accL[4][32][9];
    __shared__ float lsL[4][4];

    float4 ad4 = *reinterpret_cast<const float4*>(&ad1[n * 4]);
    int myh = j >> 3;  // head for my 8 channels
    float adn_my = (myh == 0) ? ad4.x : (myh == 1) ? ad4.y : (myh == 2) ? ad4.z : ad4.w;
    float g0 = fdec(gb[0]), g1 = fdec(gb[1]), g2 = fdec(gb[2]), g3 = fdec(gb[3]);
    float g_my = (myh == 0) ? g0 : (myh == 1) ? g1 : (myh == 2) ? g2 : g3;
    float mt = g_my + adn_my;
    float mm = mt > 0.f ? mt : NEG_SLOPE * mt;   // upper bound of e over neighbors

    float acc[8] = {0.f, 0.f, 0.f, 0.f, 0.f, 0.f, 0.f, 0.f};
    float ls = 0.f;

    for (int i = (wid << 1) | half; i < deg; i += 8) {
        int s = col[beg + i];
        float asv = as1[(size_t)s * 4 + myh];
        float e = asv + adn_my;
        e = e > 0.f ? e : NEG_SLOPE * e;
        float w = __expf(e - mm);
        ls += w;
        uint4 hv = *reinterpret_cast<const uint4*>(h1b + (size_t)s * 256 + j * 8);
        acc[0] += __uint_as_float(hv.x << 16) * w;
        acc[1] += __uint_as_float(hv.x & 0xFFFF0000u) * w;
        acc[2] += __uint_as_float(hv.y << 16) * w;
        acc[3] += __uint_as_float(hv.y & 0xFFFF0000u) * w;
        acc[4] += __uint_as_float(hv.z << 16) * w;
        acc[5] += __uint_as_float(hv.z & 0xFFFF0000u) * w;
        acc[6] += __uint_as_float(hv.w << 16) * w;
        acc[7] += __uint_as_float(hv.w & 0xFFFF0000u) * w;
    }
    #pragma unroll
    for (int e8 = 0; e8 < 8; e8++) acc[e8] += __shfl_xor(acc[e8], 32);
    ls += __shfl_xor(ls, 32);

    if (lane < 32) {
        #pragma unroll
        for (int e8 = 0; e8 < 8; e8++) accL[wid][lane][e8] = acc[e8];
        if ((lane & 7) == 0) lsL[wid][lane >> 3] = ls;
    }
    __syncthreads();

    int jj = tid >> 3, e2 = tid & 7;   // channel t = jj*8+e2
    float sum = accL[0][jj][e2] + accL[1][jj][e2] + accL[2][jj][e2] + accL[3][jj][e2];
    int hh = tid >> 6;
    float lst = lsL[0][hh] + lsL[1][hh] + lsL[2][hh] + lsL[3][hh];
    float o = sum / (lst + 1e-16f) + b1[tid];
    o = o > 0.f ? o : expm1f(o);
    out1b[(size_t)n * 256 + tid] = f2bf(o);
}

// ---------------- GEMM2 (MFMA): h2[M,40] = out1b[M,256] @ W2 ----------------
__global__ __launch_bounds__(256) void gemm2_mfma(const ushort* __restrict__ Ag,
                                                  const ushort* __restrict__ Bg,
                                                  float* __restrict__ h2) {
    __shared__ ushort Bs[48 * 264];
    int t = threadIdx.x;
    int l = t & 63, w = t >> 6;
    int lrow = l & 15, lks = l >> 4;
    for (int idx = t; idx < 48 * 264 / 8; idx += 256)
        reinterpret_cast<uint4*>(Bs)[idx] = reinterpret_cast<const uint4*>(Bg)[idx];
    __syncthreads();

    int m0 = blockIdx.x * 64 + w * 16;
    f32x4 acc[3];
    #pragma unroll
    for (int nf = 0; nf < 3; nf++) acc[nf] = (f32x4){0.f, 0.f, 0.f, 0.f};

    #pragma unroll
    for (int k0 = 0; k0 < 256; k0 += 32) {
        bf16x8 af = *reinterpret_cast<const bf16x8*>(Ag + (size_t)(m0 + lrow) * 256 + k0 + lks * 8);
        #pragma unroll
        for (int nf = 0; nf < 3; nf++) {
            bf16x8 bf = *reinterpret_cast<const bf16x8*>(&Bs[(nf * 16 + lrow) * 264 + k0 + lks * 8]);
            acc[nf] = __builtin_amdgcn_mfma_f32_16x16x32_bf16(af, bf, acc[nf], 0, 0, 0);
        }
    }
    #pragma unroll
    for (int nf = 0; nf < 3; nf++) {
        int colc = nf * 16 + lrow;
        #pragma unroll
        for (int r = 0; r < 4; r++) {
            int row = m0 + lks * 4 + r;
            if (colc < OUT_DIM && row < NNODES) h2[(size_t)row * OUT_DIM + colc] = acc[nf][r];
        }
    }
}

// ---------------- alpha2 ----------------
__global__ __launch_bounds__(256) void alpha2_kernel(const float* __restrict__ h2,
                                                     const float* __restrict__ a_src,
                                                     const float* __restrict__ a_dst,
                                                     float* __restrict__ as2,
                                                     float* __restrict__ ad2) {
    int wid = threadIdx.x >> 6, lane = threadIdx.x & 63;
    int n = blockIdx.x * 4 + wid;
    float ps = 0.f, pd = 0.f;
    if (lane < OUT_DIM) {
        float hv = h2[(size_t)n * OUT_DIM + lane];
        ps = hv * a_src[lane];
        pd = hv * a_dst[lane];
    }
    ps = wave_reduce_sum(ps);
    pd = wave_reduce_sum(pd);
    if (lane == 0) { as2[n] = ps; ad2[n] = pd; }
}

// ---------------- agg2: single-pass + bias + log_softmax ----------------
// wave per node; halves own alternating neighbors; lanes j<20 hold ch 2j,2j+1.
__global__ __launch_bounds__(256) void agg2_kernel(const float* __restrict__ h2,
                                                   const float* __restrict__ as2,
                                                   const float* __restrict__ ad2,
                                                   const int* __restrict__ rowptr,
                                                   const int* __restrict__ col,
                                                   const float* __restrict__ b2,
                                                   const uint* __restrict__ gb,
                                                   float* __restrict__ out) {
    int wid = threadIdx.x >> 6, lane = threadIdx.x & 63;
    int j = lane & 31, half = lane >> 5;
    int n = blockIdx.x * 4 + wid;
    int beg = rowptr[n], end = rowptr[n + 1];
    int deg = end - beg;
    float adn = ad2[n];
    float g = fdec(gb[4]);
    float mt = g + adn;
    float mm = mt > 0.f ? mt : NEG_SLOPE * mt;

    bool act = j < 20;
    float a0 = 0.f, a1 = 0.f, ls = 0.f;
    for (int i = half; i < deg; i += 2) {
        int s = col[beg + i];
        float e = as2[s] + adn;
        e = e > 0.f ? e : NEG_SLOPE * e;
        float wv = __expf(e - mm);
        ls += wv;
        if (act) {
            float2 hv = *reinterpret_cast<const float2*>(h2 + (size_t)s * OUT_DIM + 2 * j);
            a0 += hv.x * wv;
            a1 += hv.y * wv;
        }
    }
    a0 += __shfl_xor(a0, 32);
    a1 += __shfl_xor(a1, 32);
    ls += __shfl_xor(ls, 32);

    bool lead = lane < 20;
    float v0 = -INFINITY, v1 = -INFINITY;
    if (lead) {
        float2 bb = *reinterpret_cast<const float2*>(b2 + 2 * j);
        float dinv = 1.f / (ls + 1e-16f);
        v0 = a0 * dinv + bb.x;
        v1 = a1 * dinv + bb.y;
    }
    float mx = wave_reduce_max(fmaxf(v0, v1));
    float es = lead ? (__expf(v0 - mx) + __expf(v1 - mx)) : 0.f;
    float ssum = wave_reduce_sum(es);
    float lg = logf(ssum);
    if (lead) {
        out[(size_t)n * OUT_DIM + 2 * j] = v0 - mx - lg;
        out[(size_t)n * OUT_DIM + 2 * j + 1] = v1 - mx - lg;
    }
}

// ---------------- launch ----------------
extern "C" void kernel_launch(void* const* d_in, const int* in_sizes, int n_in,
                              void* d_out, int out_size, void* d_ws, size_t ws_size,
                              hipStream_t stream) {
    const float* x        = (const float*)d_in[0];
    const int*   ei       = (const int*)d_in[1];
    const float* W1       = (const float*)d_in[2];
    const float* att_src1 = (const float*)d_in[3];
    const float* att_dst1 = (const float*)d_in[4];
    const float* b1       = (const float*)d_in[5];
    const float* W2       = (const float*)d_in[6];
    const float* att_src2 = (const float*)d_in[7];
    const float* att_dst2 = (const float*)d_in[8];
    const float* b2       = (const float*)d_in[9];
    float* out = (float*)d_out;

    char* ws = (char*)d_ws;
    auto alloc = [&](size_t bytes) {
        char* p = ws;
        ws += (bytes + 255) & ~(size_t)255;
        return p;
    };
    ushort* xb     = (ushort*)alloc((size_t)M_PAD * 256 * 2);
    ushort* h1b    = (ushort*)alloc((size_t)M_PAD * 256 * 2);
    ushort* W1t    = (ushort*)alloc((size_t)256 * 256 * 2);
    ushort* W2tb   = (ushort*)alloc((size_t)48 * 264 * 2);
    ushort* out1b  = (ushort*)alloc((size_t)M_PAD * 256 * 2);
    float*  h2     = (float*)alloc((size_t)NNODES * OUT_DIM * 4);
    float*  as1    = (float*)alloc((size_t)NNODES * 4 * 4);
    float*  ad1    = (float*)alloc((size_t)NNODES * 4 * 4);
    float*  as2    = (float*)alloc((size_t)NNODES * 4);
    float*  ad2    = (float*)alloc((size_t)NNODES * 4);
    int*    counts = (int*)alloc((size_t)(2 * NNODES + 8) * 4);  // counts+cursor+gmax
    int*    cursor = counts + NNODES;
    uint*   gmaxb  = (uint*)(cursor + NNODES);
    int*    rowptr = (int*)alloc((size_t)(NNODES + 1) * 4);
    int*    col    = (int*)alloc((size_t)ETOT * 4);
    int*    bsum   = (int*)alloc((size_t)2 * 256 * 4);
    int*    bsum_e = bsum + 256;
    if ((size_t)(ws - (char*)d_ws) > ws_size) return;

    hipMemsetAsync(counts, 0, (size_t)(2 * NNODES + 8) * 4, stream);

    cvt_x_kernel<<<(NNODES * 256) / 2048, 256, 0, stream>>>(x, xb);
    cvt_w1t_kernel<<<256, 256, 0, stream>>>(W1, W1t);
    cvt_w2t_kernel<<<(48 * 264 + 255) / 256, 256, 0, stream>>>(W2, W2tb);

    int eb = (ETOT + 255) / 256;
    count_kernel<<<eb, 256, 0, stream>>>(ei, counts);
    scanA_kernel<<<NB_SCAN, 256, 0, stream>>>(counts, rowptr, bsum);
    scanB_kernel<<<1, 256, 0, stream>>>(bsum, bsum_e);
    scanC_kernel<<<NB_SCAN, 256, 0, stream>>>(rowptr, bsum_e);
    scatter_kernel<<<eb, 256, 0, stream>>>(ei, rowptr, cursor, col);

    dim3 g1(2, M_PAD / 128);
    gemm1_mfma<<<g1, 256, 0, stream>>>(xb, W1t, h1b);
    alpha1_kernel<<<NNODES, 256, 0, stream>>>(h1b, att_src1, att_dst1, as1, ad1);
    gmax1_kernel<<<NB_SCAN, 256, 0, stream>>>(as1, gmaxb);

    agg1_kernel<<<NNODES, 256, 0, stream>>>(h1b, as1, ad1, rowptr, col, b1, gmaxb, out1b);

    gemm2_mfma<<<M_PAD / 64, 256, 0, stream>>>(out1b, W2tb, h2);
    alpha2_kernel<<<NNODES / 4, 256, 0, stream>>>(h2, att_src2, att_dst2, as2, ad2);
    gmax2_kernel<<<NB_SCAN, 256, 0, stream>>>(as2, gmaxb);
    agg2_kernel<<<NNODES / 4, 256, 0, stream>>>(h2, as2, ad2, rowptr, col, b2, gmaxb, out);
}

// Round 4
// 279.091 us; speedup vs baseline: 2.2893x; 1.3667x over previous
//
#include <hip/hip_runtime.h>
#include <hip/hip_bf16.h>
#include <math.h>

#define NNODES 50000
#define M_PAD  50048   // 391 * 128
#define IN_DIM 256
#define HID 64
#define HEADS 4
#define OUT_DIM 40
#define NEDGES 800000
#define ETOT (NEDGES + NNODES)
#define NEG_SLOPE 0.2f
#define NB_SCAN 196    // ceil(50000/256)

typedef __attribute__((ext_vector_type(8))) short bf16x8;
typedef __attribute__((ext_vector_type(4))) float f32x4;

__device__ __forceinline__ ushort f2bf(float f) {
    uint u = __float_as_uint(f);
    u += 0x7FFF + ((u >> 16) & 1);
    return (ushort)(u >> 16);
}
__device__ __forceinline__ float bf2f(ushort u) {
    return __uint_as_float(((uint)u) << 16);
}
__device__ __forceinline__ uint fkey(float f) {   // order-preserving float->uint
    uint u = __float_as_uint(f);
    return (u & 0x80000000u) ? ~u : (u | 0x80000000u);
}
__device__ __forceinline__ float fdec(uint k) {
    return (k & 0x80000000u) ? __uint_as_float(k & 0x7fffffffu) : __uint_as_float(~k);
}
__device__ __forceinline__ float wave_reduce_max(float v) {
    #pragma unroll
    for (int off = 32; off > 0; off >>= 1) v = fmaxf(v, __shfl_xor(v, off));
    return v;
}
__device__ __forceinline__ float wave_reduce_sum(float v) {
    #pragma unroll
    for (int off = 32; off > 0; off >>= 1) v += __shfl_xor(v, off);
    return v;
}

// ---------------- W1t[n][k] = bf16(W1[k][n]) ----------------
__global__ __launch_bounds__(256) void cvt_w1t_kernel(const float* __restrict__ W1,
                                                      ushort* __restrict__ W1t) {
    int n = blockIdx.x, k = threadIdx.x;
    W1t[n * 256 + k] = f2bf(W1[k * 256 + n]);
}

// ---------------- W2tb[n][k] bf16, [48][264] padded ----------------
__global__ __launch_bounds__(256) void cvt_w2t_kernel(const float* __restrict__ W2,
                                                      ushort* __restrict__ W2tb) {
    int idx = blockIdx.x * 256 + threadIdx.x;
    if (idx >= 48 * 264) return;
    int n = idx / 264, k = idx % 264;
    W2tb[idx] = (n < OUT_DIM && k < 256) ? f2bf(W2[k * OUT_DIM + n]) : (ushort)0;
}

// ---------------- CSR build ----------------
__global__ void count_kernel(const int* __restrict__ ei, int* __restrict__ counts) {
    int idx = blockIdx.x * blockDim.x + threadIdx.x;
    if (idx >= ETOT) return;
    int d = (idx < NEDGES) ? ei[NEDGES + idx] : (idx - NEDGES);
    atomicAdd(&counts[d], 1);
}

__global__ __launch_bounds__(256) void scanA_kernel(const int* __restrict__ counts,
                                                    int* __restrict__ rowptr,
                                                    int* __restrict__ bsum) {
    __shared__ int sh[256];
    int t = threadIdx.x;
    int i = blockIdx.x * 256 + t;
    int v = (i < NNODES) ? counts[i] : 0;
    int x = v;
    sh[t] = x;
    __syncthreads();
    #pragma unroll
    for (int off = 1; off < 256; off <<= 1) {
        int y = (t >= off) ? sh[t - off] : 0;
        __syncthreads();
        x += y;
        sh[t] = x;
        __syncthreads();
    }
    if (i < NNODES) rowptr[i] = x - v;
    if (t == 255) bsum[blockIdx.x] = x;
}

__global__ __launch_bounds__(256) void scanB_kernel(int* __restrict__ bsum,
                                                    int* __restrict__ bsum_e) {
    __shared__ int sh[256];
    int t = threadIdx.x;
    int v = (t < NB_SCAN) ? bsum[t] : 0;
    int x = v;
    sh[t] = x;
    __syncthreads();
    #pragma unroll
    for (int off = 1; off < 256; off <<= 1) {
        int y = (t >= off) ? sh[t - off] : 0;
        __syncthreads();
        x += y;
        sh[t] = x;
        __syncthreads();
    }
    if (t < NB_SCAN) bsum_e[t] = x - v;
}

__global__ __launch_bounds__(256) void scanC_kernel(int* __restrict__ rowptr,
                                                    const int* __restrict__ bsum_e) {
    int i = blockIdx.x * 256 + threadIdx.x;
    if (i < NNODES) rowptr[i] += bsum_e[i >> 8];
    if (i == 0) rowptr[NNODES] = ETOT;
}

__global__ void scatter_kernel(const int* __restrict__ ei, const int* __restrict__ rowptr,
                               int* __restrict__ cursor, int* __restrict__ col) {
    int idx = blockIdx.x * blockDim.x + threadIdx.x;
    if (idx >= ETOT) return;
    int s, d;
    if (idx < NEDGES) { s = ei[idx]; d = ei[NEDGES + idx]; }
    else { s = idx - NEDGES; d = s; }
    int pos = atomicAdd(&cursor[d], 1);
    col[rowptr[d] + pos] = s;
}

// ---------------- GEMM1 fused: h1b = bf16(x) @ W1 ; as1/ad1 ; gmax1 --------
// BM=128, BN=256 (full width), BK=32, 8 waves (512 thr). A staged fp32->bf16.
__global__ __launch_bounds__(512) void gemm1_fused(const float* __restrict__ x,
                                                   const ushort* __restrict__ W1t,
                                                   const float* __restrict__ asrc,
                                                   const float* __restrict__ adst,
                                                   ushort* __restrict__ h1b,
                                                   float* __restrict__ as1,
                                                   float* __restrict__ ad1,
                                                   uint* __restrict__ gb) {
    __shared__ ushort As[128 * 32];
    __shared__ ushort Bs[256 * 32];
    __shared__ uint smax[4];
    int t = threadIdx.x;
    int l = t & 63, wid = t >> 6;
    int wm = wid & 1, wn = wid >> 1;           // wn = head (cols wn*64..wn*64+63)
    int m0 = blockIdx.x * 128;
    int lrow = l & 15, lks = l >> 4;
    int ks = lks ^ ((lrow >> 1) & 3);
    if (t < 4) smax[t] = 0u;

    f32x4 acc[4][4];
    #pragma unroll
    for (int i = 0; i < 4; i++)
        #pragma unroll
        for (int j = 0; j < 4; j++) acc[i][j] = (f32x4){0.f, 0.f, 0.f, 0.f};

    for (int k0 = 0; k0 < 256; k0 += 32) {
        // stage A: 128 rows x 32 k, fp32 -> bf16, swizzled
        #pragma unroll
        for (int i = 0; i < 2; i++) {
            int idx = t + 512 * i;
            int row = idx >> 3, c4 = idx & 7;
            int grow = m0 + row;
            float4 v = make_float4(0.f, 0.f, 0.f, 0.f);
            if (grow < NNODES) v = *reinterpret_cast<const float4*>(x + (size_t)grow * 256 + k0 + c4 * 4);
            uint2 p;
            p.x = (uint)f2bf(v.x) | ((uint)f2bf(v.y) << 16);
            p.y = (uint)f2bf(v.z) | ((uint)f2bf(v.w) << 16);
            int slot = (c4 >> 1) ^ ((row >> 1) & 3);
            *reinterpret_cast<uint2*>(&As[row * 32 + slot * 8 + (c4 & 1) * 4]) = p;
        }
        // stage B: 256 rows x 32 k bf16, swizzled
        #pragma unroll
        for (int i = 0; i < 2; i++) {
            int idx = t + 512 * i;
            int row = idx >> 2, skb = idx & 3;
            uint4 bv = *reinterpret_cast<const uint4*>(W1t + (size_t)row * 256 + k0 + skb * 8);
            int slot = skb ^ ((row >> 1) & 3);
            *reinterpret_cast<uint4*>(&Bs[row * 32 + slot * 8]) = bv;
        }
        __syncthreads();
        bf16x8 a_frag[4], b_frag[4];
        #pragma unroll
        for (int mf = 0; mf < 4; mf++)
            a_frag[mf] = *reinterpret_cast<const bf16x8*>(&As[(wm * 64 + mf * 16 + lrow) * 32 + ks * 8]);
        #pragma unroll
        for (int nf = 0; nf < 4; nf++)
            b_frag[nf] = *reinterpret_cast<const bf16x8*>(&Bs[(wn * 64 + nf * 16 + lrow) * 32 + ks * 8]);
        #pragma unroll
        for (int mf = 0; mf < 4; mf++)
            #pragma unroll
            for (int nf = 0; nf < 4; nf++)
                acc[mf][nf] = __builtin_amdgcn_mfma_f32_16x16x32_bf16(a_frag[mf], b_frag[nf], acc[mf][nf], 0, 0, 0);
        __syncthreads();
    }

    // C store (bf16)
    #pragma unroll
    for (int mf = 0; mf < 4; mf++)
        #pragma unroll
        for (int nf = 0; nf < 4; nf++) {
            int col = wn * 64 + nf * 16 + lrow;
            #pragma unroll
            for (int r = 0; r < 4; r++) {
                int row = m0 + wm * 64 + mf * 16 + lks * 4 + r;
                h1b[(size_t)row * 256 + col] = f2bf(acc[mf][nf][r]);
            }
        }

    // alpha: per-lane att weights for my 4 col-frags (head = wn)
    float a_s[4], a_d[4];
    #pragma unroll
    for (int nf = 0; nf < 4; nf++) {
        a_s[nf] = asrc[wn * 64 + nf * 16 + lrow];
        a_d[nf] = adst[wn * 64 + nf * 16 + lrow];
    }
    float ps[4][4], pd[4][4];
    #pragma unroll
    for (int mf = 0; mf < 4; mf++)
        #pragma unroll
        for (int r = 0; r < 4; r++) {
            float s = 0.f, d = 0.f;
            #pragma unroll
            for (int nf = 0; nf < 4; nf++) {
                s += acc[mf][nf][r] * a_s[nf];
                d += acc[mf][nf][r] * a_d[nf];
            }
            ps[mf][r] = s; pd[mf][r] = d;
        }
    // reduce over the 16 col-lanes (xor 1,2,4,8 stays within lks group)
    #pragma unroll
    for (int off = 1; off < 16; off <<= 1)
        #pragma unroll
        for (int mf = 0; mf < 4; mf++)
            #pragma unroll
            for (int r = 0; r < 4; r++) {
                ps[mf][r] += __shfl_xor(ps[mf][r], off);
                pd[mf][r] += __shfl_xor(pd[mf][r], off);
            }
    if (lrow == 0) {
        #pragma unroll
        for (int mf = 0; mf < 4; mf++)
            #pragma unroll
            for (int r = 0; r < 4; r++) {
                int row = m0 + wm * 64 + mf * 16 + lks * 4 + r;
                if (row < NNODES) {
                    as1[row * 4 + wn] = ps[mf][r];
                    ad1[row * 4 + wn] = pd[mf][r];
                }
            }
    }
    // gmax over valid rows (all lanes hold group sums)
    float vmax = -INFINITY;
    #pragma unroll
    for (int mf = 0; mf < 4; mf++)
        #pragma unroll
        for (int r = 0; r < 4; r++) {
            int row = m0 + wm * 64 + mf * 16 + lks * 4 + r;
            if (row < NNODES) vmax = fmaxf(vmax, ps[mf][r]);
        }
    vmax = fmaxf(vmax, __shfl_xor(vmax, 16));
    vmax = fmaxf(vmax, __shfl_xor(vmax, 32));
    if (l == 0) atomicMax(&smax[wn], fkey(vmax));
    __syncthreads();
    if (t < 4) atomicMax(&gb[t], smax[t]);
}

// ---------------- agg1: wave per node, single pass, -> bf16 out1b ----------
__global__ __launch_bounds__(256) void agg1_kernel(const ushort* __restrict__ h1b,
                                                   const float* __restrict__ as1,
                                                   const float* __restrict__ ad1,
                                                   const int* __restrict__ rowptr,
                                                   const int* __restrict__ col,
                                                   const float* __restrict__ b1,
                                                   const uint* __restrict__ gb,
                                                   ushort* __restrict__ out1b) {
    int tid = threadIdx.x;
    int lane = tid & 63, wid = tid >> 6;
    int n = blockIdx.x * 4 + wid;
    int j = lane & 31, half = lane >> 5;
    int myh = j >> 3;
    int beg = rowptr[n], deg = rowptr[n + 1] - beg;

    float adn = ad1[n * 4 + myh];
    float g = fdec(gb[myh]);
    float mt = g + adn;
    float mm = mt > 0.f ? mt : NEG_SLOPE * mt;

    float acc[8] = {0.f, 0.f, 0.f, 0.f, 0.f, 0.f, 0.f, 0.f};
    float ls = 0.f;
    for (int i = half; i < deg; i += 2) {
        int s = col[beg + i];
        float e = as1[(size_t)s * 4 + myh] + adn;
        e = e > 0.f ? e : NEG_SLOPE * e;
        float w = __expf(e - mm);
        ls += w;
        uint4 hv = *reinterpret_cast<const uint4*>(h1b + (size_t)s * 256 + j * 8);
        acc[0] += __uint_as_float(hv.x << 16) * w;
        acc[1] += __uint_as_float(hv.x & 0xFFFF0000u) * w;
        acc[2] += __uint_as_float(hv.y << 16) * w;
        acc[3] += __uint_as_float(hv.y & 0xFFFF0000u) * w;
        acc[4] += __uint_as_float(hv.z << 16) * w;
        acc[5] += __uint_as_float(hv.z & 0xFFFF0000u) * w;
        acc[6] += __uint_as_float(hv.w << 16) * w;
        acc[7] += __uint_as_float(hv.w & 0xFFFF0000u) * w;
    }
    #pragma unroll
    for (int e8 = 0; e8 < 8; e8++) acc[e8] += __shfl_xor(acc[e8], 32);
    ls += __shfl_xor(ls, 32);

    if (lane < 32) {
        float dinv = 1.f / (ls + 1e-16f);
        float4 bA = *reinterpret_cast<const float4*>(b1 + j * 8);
        float4 bB = *reinterpret_cast<const float4*>(b1 + j * 8 + 4);
        float o[8];
        o[0] = acc[0] * dinv + bA.x; o[1] = acc[1] * dinv + bA.y;
        o[2] = acc[2] * dinv + bA.z; o[3] = acc[3] * dinv + bA.w;
        o[4] = acc[4] * dinv + bB.x; o[5] = acc[5] * dinv + bB.y;
        o[6] = acc[6] * dinv + bB.z; o[7] = acc[7] * dinv + bB.w;
        uint4 pk;
        #pragma unroll
        for (int e8 = 0; e8 < 8; e8++) o[e8] = o[e8] > 0.f ? o[e8] : expm1f(o[e8]);
        pk.x = (uint)f2bf(o[0]) | ((uint)f2bf(o[1]) << 16);
        pk.y = (uint)f2bf(o[2]) | ((uint)f2bf(o[3]) << 16);
        pk.z = (uint)f2bf(o[4]) | ((uint)f2bf(o[5]) << 16);
        pk.w = (uint)f2bf(o[6]) | ((uint)f2bf(o[7]) << 16);
        *reinterpret_cast<uint4*>(out1b + (size_t)n * 256 + j * 8) = pk;
    }
}

// ---------------- GEMM2 fused: h2b = out1b @ W2 (bf16) ; as2/ad2 ; gmax2 ---
__global__ __launch_bounds__(256) void gemm2_fused(const ushort* __restrict__ Ag,
                                                   const ushort* __restrict__ Bg,
                                                   const float* __restrict__ a2s,
                                                   const float* __restrict__ a2d,
                                                   ushort* __restrict__ h2b,
                                                   float* __restrict__ as2,
                                                   float* __restrict__ ad2,
                                                   uint* __restrict__ gb) {
    __shared__ ushort Bs[48 * 264];
    __shared__ uint smax;
    int t = threadIdx.x;
    int l = t & 63, w = t >> 6;
    int lrow = l & 15, lks = l >> 4;
    if (t == 0) smax = 0u;
    for (int idx = t; idx < 48 * 264 / 8; idx += 256)
        reinterpret_cast<uint4*>(Bs)[idx] = reinterpret_cast<const uint4*>(Bg)[idx];
    __syncthreads();

    int m0 = blockIdx.x * 64 + w * 16;
    f32x4 acc[3];
    #pragma unroll
    for (int nf = 0; nf < 3; nf++) acc[nf] = (f32x4){0.f, 0.f, 0.f, 0.f};

    #pragma unroll
    for (int k0 = 0; k0 < 256; k0 += 32) {
        bf16x8 af = *reinterpret_cast<const bf16x8*>(Ag + (size_t)(m0 + lrow) * 256 + k0 + lks * 8);
        #pragma unroll
        for (int nf = 0; nf < 3; nf++) {
            bf16x8 bf = *reinterpret_cast<const bf16x8*>(&Bs[(nf * 16 + lrow) * 264 + k0 + lks * 8]);
            acc[nf] = __builtin_amdgcn_mfma_f32_16x16x32_bf16(af, bf, acc[nf], 0, 0, 0);
        }
    }

    // att weights (cols >= 40 masked to 0)
    float a_s[3], a_d[3];
    #pragma unroll
    for (int nf = 0; nf < 3; nf++) {
        int c = nf * 16 + lrow;
        a_s[nf] = (c < OUT_DIM) ? a2s[c] : 0.f;
        a_d[nf] = (c < OUT_DIM) ? a2d[c] : 0.f;
    }
    float ps[4], pd[4];
    #pragma unroll
    for (int r = 0; r < 4; r++) {
        float s = 0.f, d = 0.f;
        #pragma unroll
        for (int nf = 0; nf < 3; nf++) { s += acc[nf][r] * a_s[nf]; d += acc[nf][r] * a_d[nf]; }
        ps[r] = s; pd[r] = d;
    }
    // h2b store (bf16)
    #pragma unroll
    for (int nf = 0; nf < 3; nf++) {
        int c = nf * 16 + lrow;
        if (c < OUT_DIM) {
            #pragma unroll
            for (int r = 0; r < 4; r++) {
                int row = m0 + lks * 4 + r;
                if (row < NNODES) h2b[(size_t)row * OUT_DIM + c] = f2bf(acc[nf][r]);
            }
        }
    }
    // reduce over 16 col-lanes
    #pragma unroll
    for (int off = 1; off < 16; off <<= 1)
        #pragma unroll
        for (int r = 0; r < 4; r++) {
            ps[r] += __shfl_xor(ps[r], off);
            pd[r] += __shfl_xor(pd[r], off);
        }
    if (lrow == 0) {
        #pragma unroll
        for (int r = 0; r < 4; r++) {
            int row = m0 + lks * 4 + r;
            if (row < NNODES) { as2[row] = ps[r]; ad2[row] = pd[r]; }
        }
    }
    float vmax = -INFINITY;
    #pragma unroll
    for (int r = 0; r < 4; r++) {
        int row = m0 + lks * 4 + r;
        if (row < NNODES) vmax = fmaxf(vmax, ps[r]);
    }
    vmax = fmaxf(vmax, __shfl_xor(vmax, 16));
    vmax = fmaxf(vmax, __shfl_xor(vmax, 32));
    if (l == 0) atomicMax(&smax, fkey(vmax));
    __syncthreads();
    if (t == 0) atomicMax(&gb[4], smax);
}

// ---------------- agg2: wave per node + bias + log_softmax ----------------
__global__ __launch_bounds__(256) void agg2_kernel(const ushort* __restrict__ h2b,
                                                   const float* __restrict__ as2,
                                                   const float* __restrict__ ad2,
                                                   const int* __restrict__ rowptr,
                                                   const int* __restrict__ col,
                                                   const float* __restrict__ b2,
                                                   const uint* __restrict__ gb,
                                                   float* __restrict__ out) {
    int tid = threadIdx.x;
    int lane = tid & 63, wid = tid >> 6;
    int n = blockIdx.x * 4 + wid;
    int j = lane & 31, half = lane >> 5;
    int beg = rowptr[n], deg = rowptr[n + 1] - beg;
    float adn = ad2[n];
    float g = fdec(gb[4]);
    float mt = g + adn;
    float mm = mt > 0.f ? mt : NEG_SLOPE * mt;

    bool act = j < 20;
    float a0 = 0.f, a1 = 0.f, ls = 0.f;
    for (int i = half; i < deg; i += 2) {
        int s = col[beg + i];
        float e = as2[s] + adn;
        e = e > 0.f ? e : NEG_SLOPE * e;
        float wv = __expf(e - mm);
        ls += wv;
        if (act) {
            uint hv = *reinterpret_cast<const uint*>(h2b + (size_t)s * OUT_DIM + j * 2);
            a0 += __uint_as_float(hv << 16) * wv;
            a1 += __uint_as_float(hv & 0xFFFF0000u) * wv;
        }
    }
    a0 += __shfl_xor(a0, 32);
    a1 += __shfl_xor(a1, 32);
    ls += __shfl_xor(ls, 32);

    bool lead = lane < 20;
    float v0 = -INFINITY, v1 = -INFINITY;
    if (lead) {
        float2 bb = *reinterpret_cast<const float2*>(b2 + 2 * j);
        float dinv = 1.f / (ls + 1e-16f);
        v0 = a0 * dinv + bb.x;
        v1 = a1 * dinv + bb.y;
    }
    float mx = wave_reduce_max(fmaxf(v0, v1));
    float es = lead ? (__expf(v0 - mx) + __expf(v1 - mx)) : 0.f;
    float ssum = wave_reduce_sum(es);
    float lg = logf(ssum);
    if (lead) {
        float2 o2 = make_float2(v0 - mx - lg, v1 - mx - lg);
        *reinterpret_cast<float2*>(out + (size_t)n * OUT_DIM + 2 * j) = o2;
    }
}

// ---------------- launch ----------------
extern "C" void kernel_launch(void* const* d_in, const int* in_sizes, int n_in,
                              void* d_out, int out_size, void* d_ws, size_t ws_size,
                              hipStream_t stream) {
    const float* x        = (const float*)d_in[0];
    const int*   ei       = (const int*)d_in[1];
    const float* W1       = (const float*)d_in[2];
    const float* att_src1 = (const float*)d_in[3];
    const float* att_dst1 = (const float*)d_in[4];
    const float* b1       = (const float*)d_in[5];
    const float* W2       = (const float*)d_in[6];
    const float* att_src2 = (const float*)d_in[7];
    const float* att_dst2 = (const float*)d_in[8];
    const float* b2       = (const float*)d_in[9];
    float* out = (float*)d_out;

    char* ws = (char*)d_ws;
    auto alloc = [&](size_t bytes) {
        char* p = ws;
        ws += (bytes + 255) & ~(size_t)255;
        return p;
    };
    ushort* h1b    = (ushort*)alloc((size_t)M_PAD * 256 * 2);
    ushort* out1b  = (ushort*)alloc((size_t)M_PAD * 256 * 2);
    ushort* W1t    = (ushort*)alloc((size_t)256 * 256 * 2);
    ushort* W2tb   = (ushort*)alloc((size_t)48 * 264 * 2);
    ushort* h2b    = (ushort*)alloc((size_t)NNODES * OUT_DIM * 2);
    float*  as1    = (float*)alloc((size_t)NNODES * 4 * 4);
    float*  ad1    = (float*)alloc((size_t)NNODES * 4 * 4);
    float*  as2    = (float*)alloc((size_t)NNODES * 4);
    float*  ad2    = (float*)alloc((size_t)NNODES * 4);
    int*    counts = (int*)alloc((size_t)(2 * NNODES + 8) * 4);  // counts+cursor+gmax
    int*    cursor = counts + NNODES;
    uint*   gmaxb  = (uint*)(cursor + NNODES);
    int*    rowptr = (int*)alloc((size_t)(NNODES + 1) * 4);
    int*    col    = (int*)alloc((size_t)ETOT * 4);
    int*    bsum   = (int*)alloc((size_t)2 * 256 * 4);
    int*    bsum_e = bsum + 256;
    if ((size_t)(ws - (char*)d_ws) > ws_size) return;

    hipMemsetAsync(counts, 0, (size_t)(2 * NNODES + 8) * 4, stream);

    cvt_w1t_kernel<<<256, 256, 0, stream>>>(W1, W1t);
    cvt_w2t_kernel<<<(48 * 264 + 255) / 256, 256, 0, stream>>>(W2, W2tb);

    int eb = (ETOT + 255) / 256;
    count_kernel<<<eb, 256, 0, stream>>>(ei, counts);
    scanA_kernel<<<NB_SCAN, 256, 0, stream>>>(counts, rowptr, bsum);
    scanB_kernel<<<1, 256, 0, stream>>>(bsum, bsum_e);
    scanC_kernel<<<NB_SCAN, 256, 0, stream>>>(rowptr, bsum_e);
    scatter_kernel<<<eb, 256, 0, stream>>>(ei, rowptr, cursor, col);

    gemm1_fused<<<M_PAD / 128, 512, 0, stream>>>(x, W1t, att_src1, att_dst1,
                                                 h1b, as1, ad1, gmaxb);
    agg1_kernel<<<NNODES / 4, 256, 0, stream>>>(h1b, as1, ad1, rowptr, col, b1, gmaxb, out1b);

    gemm2_fused<<<M_PAD / 64, 256, 0, stream>>>(out1b, W2tb, att_src2, att_dst2,
                                                h2b, as2, ad2, gmaxb);
    agg2_kernel<<<NNODES / 4, 256, 0, stream>>>(h2b, as2, ad2, rowptr, col, b2, gmaxb, out);
}

// Round 6
// 253.463 us; speedup vs baseline: 2.5208x; 1.1011x over previous
//
#include <hip/hip_runtime.h>
#include <hip/hip_bf16.h>
#include <math.h>

#define NNODES 50000
#define M_PAD  50048   // 391 * 128
#define IN_DIM 256
#define HID 64
#define HEADS 4
#define OUT_DIM 40
#define NEDGES 800000
#define ETOT (NEDGES + NNODES)
#define NEG_SLOPE 0.2f
#define NB_SCAN 196    // ceil(50000/256)

typedef __attribute__((ext_vector_type(8))) short bf16x8;
typedef __attribute__((ext_vector_type(4))) float f32x4;

__device__ __forceinline__ ushort f2bf(float f) {
    uint u = __float_as_uint(f);
    u += 0x7FFF + ((u >> 16) & 1);
    return (ushort)(u >> 16);
}
__device__ __forceinline__ float bf2f(ushort u) {
    return __uint_as_float(((uint)u) << 16);
}
__device__ __forceinline__ uint fkey(float f) {   // order-preserving float->uint
    uint u = __float_as_uint(f);
    return (u & 0x80000000u) ? ~u : (u | 0x80000000u);
}
__device__ __forceinline__ float fdec(uint k) {
    return (k & 0x80000000u) ? __uint_as_float(k & 0x7fffffffu) : __uint_as_float(~k);
}
__device__ __forceinline__ float wave_reduce_max(float v) {
    #pragma unroll
    for (int off = 32; off > 0; off >>= 1) v = fmaxf(v, __shfl_xor(v, off));
    return v;
}
__device__ __forceinline__ float wave_reduce_sum(float v) {
    #pragma unroll
    for (int off = 32; off > 0; off >>= 1) v += __shfl_xor(v, off);
    return v;
}

// NOTE: parameter renamed wgt — a param named `w` is rewritten inside `.w`
// member accesses by the preprocessor (round-5 compile failure).
__device__ __forceinline__ void accum8(float* acc, uint4 hv, float wgt) {
    acc[0] = fmaf(__uint_as_float(hv.x << 16), wgt, acc[0]);
    acc[1] = fmaf(__uint_as_float(hv.x & 0xFFFF0000u), wgt, acc[1]);
    acc[2] = fmaf(__uint_as_float(hv.y << 16), wgt, acc[2]);
    acc[3] = fmaf(__uint_as_float(hv.y & 0xFFFF0000u), wgt, acc[3]);
    acc[4] = fmaf(__uint_as_float(hv.z << 16), wgt, acc[4]);
    acc[5] = fmaf(__uint_as_float(hv.z & 0xFFFF0000u), wgt, acc[5]);
    acc[6] = fmaf(__uint_as_float(hv.w << 16), wgt, acc[6]);
    acc[7] = fmaf(__uint_as_float(hv.w & 0xFFFF0000u), wgt, acc[7]);
}

// ---------------- W1t[n][k] = bf16(W1[k][n]) ----------------
__global__ __launch_bounds__(256) void cvt_w1t_kernel(const float* __restrict__ W1,
                                                      ushort* __restrict__ W1t) {
    int n = blockIdx.x, k = threadIdx.x;
    W1t[n * 256 + k] = f2bf(W1[k * 256 + n]);
}

// ---------------- W2tb[n][k] bf16, [48][264] padded ----------------
__global__ __launch_bounds__(256) void cvt_w2t_kernel(const float* __restrict__ W2,
                                                      ushort* __restrict__ W2tb) {
    int idx = blockIdx.x * 256 + threadIdx.x;
    if (idx >= 48 * 264) return;
    int n = idx / 264, k = idx % 264;
    W2tb[idx] = (n < OUT_DIM && k < 256) ? f2bf(W2[k * OUT_DIM + n]) : (ushort)0;
}

// ---------------- CSR build ----------------
__global__ void count_kernel(const int* __restrict__ ei, int* __restrict__ counts) {
    int idx = blockIdx.x * blockDim.x + threadIdx.x;
    if (idx >= ETOT) return;
    int d = (idx < NEDGES) ? ei[NEDGES + idx] : (idx - NEDGES);
    atomicAdd(&counts[d], 1);
}

__global__ __launch_bounds__(256) void scanA_kernel(const int* __restrict__ counts,
                                                    int* __restrict__ rowptr,
                                                    int* __restrict__ bsum) {
    __shared__ int sh[256];
    int t = threadIdx.x;
    int i = blockIdx.x * 256 + t;
    int v = (i < NNODES) ? counts[i] : 0;
    int x = v;
    sh[t] = x;
    __syncthreads();
    #pragma unroll
    for (int off = 1; off < 256; off <<= 1) {
        int y = (t >= off) ? sh[t - off] : 0;
        __syncthreads();
        x += y;
        sh[t] = x;
        __syncthreads();
    }
    if (i < NNODES) rowptr[i] = x - v;
    if (t == 255) bsum[blockIdx.x] = x;
}

__global__ __launch_bounds__(256) void scanB_kernel(int* __restrict__ bsum,
                                                    int* __restrict__ bsum_e) {
    __shared__ int sh[256];
    int t = threadIdx.x;
    int v = (t < NB_SCAN) ? bsum[t] : 0;
    int x = v;
    sh[t] = x;
    __syncthreads();
    #pragma unroll
    for (int off = 1; off < 256; off <<= 1) {
        int y = (t >= off) ? sh[t - off] : 0;
        __syncthreads();
        x += y;
        sh[t] = x;
        __syncthreads();
    }
    if (t < NB_SCAN) bsum_e[t] = x - v;
}

__global__ __launch_bounds__(256) void scanC_kernel(int* __restrict__ rowptr,
                                                    const int* __restrict__ bsum_e,
                                                    int* __restrict__ cursor) {
    int i = blockIdx.x * 256 + threadIdx.x;
    if (i < NNODES) {
        int v = rowptr[i] + bsum_e[i >> 8];
        rowptr[i] = v;
        cursor[i] = v;
    }
    if (i == 0) rowptr[NNODES] = ETOT;
}

__global__ void scatter_kernel(const int* __restrict__ ei,
                               int* __restrict__ cursor, int* __restrict__ col) {
    int idx = blockIdx.x * blockDim.x + threadIdx.x;
    if (idx >= ETOT) return;
    int s, d;
    if (idx < NEDGES) { s = ei[idx]; d = ei[NEDGES + idx]; }
    else { s = idx - NEDGES; d = s; }
    int pos = atomicAdd(&cursor[d], 1);
    col[pos] = s;
}

// ---------------- GEMM1 fused: h1b = bf16(x) @ W1 ; as1/ad1 ; gmax1 --------
__global__ __launch_bounds__(512) void gemm1_fused(const float* __restrict__ x,
                                                   const ushort* __restrict__ W1t,
                                                   const float* __restrict__ asrc,
                                                   const float* __restrict__ adst,
                                                   ushort* __restrict__ h1b,
                                                   float* __restrict__ as1,
                                                   float* __restrict__ ad1,
                                                   uint* __restrict__ gb) {
    __shared__ ushort As[128 * 32];
    __shared__ ushort Bs[256 * 32];
    __shared__ uint smax[4];
    int t = threadIdx.x;
    int l = t & 63, wid = t >> 6;
    int wm = wid & 1, wn = wid >> 1;           // wn = head (cols wn*64..wn*64+63)
    int m0 = blockIdx.x * 128;
    int lrow = l & 15, lks = l >> 4;
    int ks = lks ^ ((lrow >> 1) & 3);
    if (t < 4) smax[t] = 0u;

    f32x4 acc[4][4];
    #pragma unroll
    for (int i = 0; i < 4; i++)
        #pragma unroll
        for (int j = 0; j < 4; j++) acc[i][j] = (f32x4){0.f, 0.f, 0.f, 0.f};

    for (int k0 = 0; k0 < 256; k0 += 32) {
        #pragma unroll
        for (int i = 0; i < 2; i++) {
            int idx = t + 512 * i;
            int row = idx >> 3, c4 = idx & 7;
            int grow = m0 + row;
            float4 v = make_float4(0.f, 0.f, 0.f, 0.f);
            if (grow < NNODES) v = *reinterpret_cast<const float4*>(x + (size_t)grow * 256 + k0 + c4 * 4);
            uint2 p;
            p.x = (uint)f2bf(v.x) | ((uint)f2bf(v.y) << 16);
            p.y = (uint)f2bf(v.z) | ((uint)f2bf(v.w) << 16);
            int slot = (c4 >> 1) ^ ((row >> 1) & 3);
            *reinterpret_cast<uint2*>(&As[row * 32 + slot * 8 + (c4 & 1) * 4]) = p;
        }
        #pragma unroll
        for (int i = 0; i < 2; i++) {
            int idx = t + 512 * i;
            int row = idx >> 2, skb = idx & 3;
            uint4 bv = *reinterpret_cast<const uint4*>(W1t + (size_t)row * 256 + k0 + skb * 8);
            int slot = skb ^ ((row >> 1) & 3);
            *reinterpret_cast<uint4*>(&Bs[row * 32 + slot * 8]) = bv;
        }
        __syncthreads();
        bf16x8 a_frag[4], b_frag[4];
        #pragma unroll
        for (int mf = 0; mf < 4; mf++)
            a_frag[mf] = *reinterpret_cast<const bf16x8*>(&As[(wm * 64 + mf * 16 + lrow) * 32 + ks * 8]);
        #pragma unroll
        for (int nf = 0; nf < 4; nf++)
            b_frag[nf] = *reinterpret_cast<const bf16x8*>(&Bs[(wn * 64 + nf * 16 + lrow) * 32 + ks * 8]);
        #pragma unroll
        for (int mf = 0; mf < 4; mf++)
            #pragma unroll
            for (int nf = 0; nf < 4; nf++)
                acc[mf][nf] = __builtin_amdgcn_mfma_f32_16x16x32_bf16(a_frag[mf], b_frag[nf], acc[mf][nf], 0, 0, 0);
        __syncthreads();
    }

    #pragma unroll
    for (int mf = 0; mf < 4; mf++)
        #pragma unroll
        for (int nf = 0; nf < 4; nf++) {
            int col = wn * 64 + nf * 16 + lrow;
            #pragma unroll
            for (int r = 0; r < 4; r++) {
                int row = m0 + wm * 64 + mf * 16 + lks * 4 + r;
                h1b[(size_t)row * 256 + col] = f2bf(acc[mf][nf][r]);
            }
        }

    float a_s[4], a_d[4];
    #pragma unroll
    for (int nf = 0; nf < 4; nf++) {
        a_s[nf] = asrc[wn * 64 + nf * 16 + lrow];
        a_d[nf] = adst[wn * 64 + nf * 16 + lrow];
    }
    float ps[4][4], pd[4][4];
    #pragma unroll
    for (int mf = 0; mf < 4; mf++)
        #pragma unroll
        for (int r = 0; r < 4; r++) {
            float s = 0.f, d = 0.f;
            #pragma unroll
            for (int nf = 0; nf < 4; nf++) {
                s += acc[mf][nf][r] * a_s[nf];
                d += acc[mf][nf][r] * a_d[nf];
            }
            ps[mf][r] = s; pd[mf][r] = d;
        }
    #pragma unroll
    for (int off = 1; off < 16; off <<= 1)
        #pragma unroll
        for (int mf = 0; mf < 4; mf++)
            #pragma unroll
            for (int r = 0; r < 4; r++) {
                ps[mf][r] += __shfl_xor(ps[mf][r], off);
                pd[mf][r] += __shfl_xor(pd[mf][r], off);
            }
    if (lrow == 0) {
        #pragma unroll
        for (int mf = 0; mf < 4; mf++)
            #pragma unroll
            for (int r = 0; r < 4; r++) {
                int row = m0 + wm * 64 + mf * 16 + lks * 4 + r;
                if (row < NNODES) {
                    as1[row * 4 + wn] = ps[mf][r];
                    ad1[row * 4 + wn] = pd[mf][r];
                }
            }
    }
    float vmax = -INFINITY;
    #pragma unroll
    for (int mf = 0; mf < 4; mf++)
        #pragma unroll
        for (int r = 0; r < 4; r++) {
            int row = m0 + wm * 64 + mf * 16 + lks * 4 + r;
            if (row < NNODES) vmax = fmaxf(vmax, ps[mf][r]);
        }
    vmax = fmaxf(vmax, __shfl_xor(vmax, 16));
    vmax = fmaxf(vmax, __shfl_xor(vmax, 32));
    if (l == 0) atomicMax(&smax[wn], fkey(vmax));
    __syncthreads();
    if (t < 4) atomicMax(&gb[t], smax[t]);
}

// ---------------- agg1: wave per node, 4-deep pipelined, -> bf16 out1b -----
__global__ __launch_bounds__(256) void agg1_kernel(const ushort* __restrict__ h1b,
                                                   const float* __restrict__ as1,
                                                   const float* __restrict__ ad1,
                                                   const int* __restrict__ rowptr,
                                                   const int* __restrict__ col,
                                                   const float* __restrict__ b1,
                                                   const uint* __restrict__ gb,
                                                   ushort* __restrict__ out1b) {
    int tid = threadIdx.x;
    int lane = tid & 63, wid = tid >> 6;
    int n = blockIdx.x * 4 + wid;
    int j = lane & 31, half = lane >> 5;
    int myh = j >> 3;
    int beg = rowptr[n], deg = rowptr[n + 1] - beg;

    float adn = ad1[n * 4 + myh];
    float g = fdec(gb[myh]);
    float mt = g + adn;
    float mm = mt > 0.f ? mt : NEG_SLOPE * mt;

    float acc[8] = {0.f, 0.f, 0.f, 0.f, 0.f, 0.f, 0.f, 0.f};
    float ls = 0.f;
    const int* cp = col + beg;

    int i = half;
    // 4 neighbors per half-wave per iteration: batched independent loads
    for (; i + 6 < deg; i += 8) {
        int s0 = cp[i], s1 = cp[i + 2], s2 = cp[i + 4], s3 = cp[i + 6];
        float q0 = as1[(size_t)s0 * 4 + myh];
        float q1 = as1[(size_t)s1 * 4 + myh];
        float q2 = as1[(size_t)s2 * 4 + myh];
        float q3 = as1[(size_t)s3 * 4 + myh];
        uint4 h0 = *reinterpret_cast<const uint4*>(h1b + (size_t)s0 * 256 + j * 8);
        uint4 h1v = *reinterpret_cast<const uint4*>(h1b + (size_t)s1 * 256 + j * 8);
        uint4 h2v = *reinterpret_cast<const uint4*>(h1b + (size_t)s2 * 256 + j * 8);
        uint4 h3v = *reinterpret_cast<const uint4*>(h1b + (size_t)s3 * 256 + j * 8);
        float e0 = q0 + adn; e0 = e0 > 0.f ? e0 : NEG_SLOPE * e0; float w0 = __expf(e0 - mm);
        float e1 = q1 + adn; e1 = e1 > 0.f ? e1 : NEG_SLOPE * e1; float w1 = __expf(e1 - mm);
        float e2 = q2 + adn; e2 = e2 > 0.f ? e2 : NEG_SLOPE * e2; float w2 = __expf(e2 - mm);
        float e3 = q3 + adn; e3 = e3 > 0.f ? e3 : NEG_SLOPE * e3; float w3 = __expf(e3 - mm);
        ls += (w0 + w1) + (w2 + w3);
        accum8(acc, h0, w0);
        accum8(acc, h1v, w1);
        accum8(acc, h2v, w2);
        accum8(acc, h3v, w3);
    }
    for (; i < deg; i += 2) {
        int s = cp[i];
        float e = as1[(size_t)s * 4 + myh] + adn;
        e = e > 0.f ? e : NEG_SLOPE * e;
        float w = __expf(e - mm);
        ls += w;
        uint4 hv = *reinterpret_cast<const uint4*>(h1b + (size_t)s * 256 + j * 8);
        accum8(acc, hv, w);
    }
    #pragma unroll
    for (int e8 = 0; e8 < 8; e8++) acc[e8] += __shfl_xor(acc[e8], 32);
    ls += __shfl_xor(ls, 32);

    if (lane < 32) {
        float dinv = 1.f / (ls + 1e-16f);
        float4 bA = *reinterpret_cast<const float4*>(b1 + j * 8);
        float4 bB = *reinterpret_cast<const float4*>(b1 + j * 8 + 4);
        float o[8];
        o[0] = acc[0] * dinv + bA.x; o[1] = acc[1] * dinv + bA.y;
        o[2] = acc[2] * dinv + bA.z; o[3] = acc[3] * dinv + bA.w;
        o[4] = acc[4] * dinv + bB.x; o[5] = acc[5] * dinv + bB.y;
        o[6] = acc[6] * dinv + bB.z; o[7] = acc[7] * dinv + bB.w;
        uint4 pk;
        #pragma unroll
        for (int e8 = 0; e8 < 8; e8++) o[e8] = o[e8] > 0.f ? o[e8] : expm1f(o[e8]);
        pk.x = (uint)f2bf(o[0]) | ((uint)f2bf(o[1]) << 16);
        pk.y = (uint)f2bf(o[2]) | ((uint)f2bf(o[3]) << 16);
        pk.z = (uint)f2bf(o[4]) | ((uint)f2bf(o[5]) << 16);
        pk.w = (uint)f2bf(o[6]) | ((uint)f2bf(o[7]) << 16);
        *reinterpret_cast<uint4*>(out1b + (size_t)n * 256 + j * 8) = pk;
    }
}

// ---------------- GEMM2 fused: h2b = out1b @ W2 (bf16) ; as2/ad2 ; gmax2 ---
__global__ __launch_bounds__(256) void gemm2_fused(const ushort* __restrict__ Ag,
                                                   const ushort* __restrict__ Bg,
                                                   const float* __restrict__ a2s,
                                                   const float* __restrict__ a2d,
                                                   ushort* __restrict__ h2b,
                                                   float* __restrict__ as2,
                                                   float* __restrict__ ad2,
                                                   uint* __restrict__ gb) {
    __shared__ ushort Bs[48 * 264];
    __shared__ uint smax;
    int t = threadIdx.x;
    int l = t & 63, w = t >> 6;
    int lrow = l & 15, lks = l >> 4;
    if (t == 0) smax = 0u;
    for (int idx = t; idx < 48 * 264 / 8; idx += 256)
        reinterpret_cast<uint4*>(Bs)[idx] = reinterpret_cast<const uint4*>(Bg)[idx];
    __syncthreads();

    int m0 = blockIdx.x * 64 + w * 16;
    f32x4 acc[3];
    #pragma unroll
    for (int nf = 0; nf < 3; nf++) acc[nf] = (f32x4){0.f, 0.f, 0.f, 0.f};

    #pragma unroll
    for (int k0 = 0; k0 < 256; k0 += 32) {
        bf16x8 af = *reinterpret_cast<const bf16x8*>(Ag + (size_t)(m0 + lrow) * 256 + k0 + lks * 8);
        #pragma unroll
        for (int nf = 0; nf < 3; nf++) {
            bf16x8 bf = *reinterpret_cast<const bf16x8*>(&Bs[(nf * 16 + lrow) * 264 + k0 + lks * 8]);
            acc[nf] = __builtin_amdgcn_mfma_f32_16x16x32_bf16(af, bf, acc[nf], 0, 0, 0);
        }
    }

    float a_s[3], a_d[3];
    #pragma unroll
    for (int nf = 0; nf < 3; nf++) {
        int c = nf * 16 + lrow;
        a_s[nf] = (c < OUT_DIM) ? a2s[c] : 0.f;
        a_d[nf] = (c < OUT_DIM) ? a2d[c] : 0.f;
    }
    float ps[4], pd[4];
    #pragma unroll
    for (int r = 0; r < 4; r++) {
        float s = 0.f, d = 0.f;
        #pragma unroll
        for (int nf = 0; nf < 3; nf++) { s += acc[nf][r] * a_s[nf]; d += acc[nf][r] * a_d[nf]; }
        ps[r] = s; pd[r] = d;
    }
    #pragma unroll
    for (int nf = 0; nf < 3; nf++) {
        int c = nf * 16 + lrow;
        if (c < OUT_DIM) {
            #pragma unroll
            for (int r = 0; r < 4; r++) {
                int row = m0 + lks * 4 + r;
                if (row < NNODES) h2b[(size_t)row * OUT_DIM + c] = f2bf(acc[nf][r]);
            }
        }
    }
    #pragma unroll
    for (int off = 1; off < 16; off <<= 1)
        #pragma unroll
        for (int r = 0; r < 4; r++) {
            ps[r] += __shfl_xor(ps[r], off);
            pd[r] += __shfl_xor(pd[r], off);
        }
    if (lrow == 0) {
        #pragma unroll
        for (int r = 0; r < 4; r++) {
            int row = m0 + lks * 4 + r;
            if (row < NNODES) { as2[row] = ps[r]; ad2[row] = pd[r]; }
        }
    }
    float vmax = -INFINITY;
    #pragma unroll
    for (int r = 0; r < 4; r++) {
        int row = m0 + lks * 4 + r;
        if (row < NNODES) vmax = fmaxf(vmax, ps[r]);
    }
    vmax = fmaxf(vmax, __shfl_xor(vmax, 16));
    vmax = fmaxf(vmax, __shfl_xor(vmax, 32));
    if (l == 0) atomicMax(&smax, fkey(vmax));
    __syncthreads();
    if (t == 0) atomicMax(&gb[4], smax);
}

// ---------------- agg2: wave per node, 4-deep pipelined + log_softmax ------
__global__ __launch_bounds__(256) void agg2_kernel(const ushort* __restrict__ h2b,
                                                   const float* __restrict__ as2,
                                                   const float* __restrict__ ad2,
                                                   const int* __restrict__ rowptr,
                                                   const int* __restrict__ col,
                                                   const float* __restrict__ b2,
                                                   const uint* __restrict__ gb,
                                                   float* __restrict__ out) {
    int tid = threadIdx.x;
    int lane = tid & 63, wid = tid >> 6;
    int n = blockIdx.x * 4 + wid;
    int j = lane & 31, half = lane >> 5;
    int beg = rowptr[n], deg = rowptr[n + 1] - beg;
    float adn = ad2[n];
    float g = fdec(gb[4]);
    float mt = g + adn;
    float mm = mt > 0.f ? mt : NEG_SLOPE * mt;

    bool act = j < 20;
    float a0 = 0.f, a1 = 0.f, ls = 0.f;
    const int* cp = col + beg;

    int i = half;
    for (; i + 6 < deg; i += 8) {
        int s0 = cp[i], s1 = cp[i + 2], s2 = cp[i + 4], s3 = cp[i + 6];
        float q0 = as2[s0], q1 = as2[s1], q2 = as2[s2], q3 = as2[s3];
        uint v0 = 0, v1 = 0, v2 = 0, v3 = 0;
        if (act) {
            v0 = *reinterpret_cast<const uint*>(h2b + (size_t)s0 * OUT_DIM + j * 2);
            v1 = *reinterpret_cast<const uint*>(h2b + (size_t)s1 * OUT_DIM + j * 2);
            v2 = *reinterpret_cast<const uint*>(h2b + (size_t)s2 * OUT_DIM + j * 2);
            v3 = *reinterpret_cast<const uint*>(h2b + (size_t)s3 * OUT_DIM + j * 2);
        }
        float e0 = q0 + adn; e0 = e0 > 0.f ? e0 : NEG_SLOPE * e0; float w0 = __expf(e0 - mm);
        float e1 = q1 + adn; e1 = e1 > 0.f ? e1 : NEG_SLOPE * e1; float w1 = __expf(e1 - mm);
        float e2 = q2 + adn; e2 = e2 > 0.f ? e2 : NEG_SLOPE * e2; float w2 = __expf(e2 - mm);
        float e3 = q3 + adn; e3 = e3 > 0.f ? e3 : NEG_SLOPE * e3; float w3 = __expf(e3 - mm);
        ls += (w0 + w1) + (w2 + w3);
        a0 = fmaf(__uint_as_float(v0 << 16), w0, a0);
        a1 = fmaf(__uint_as_float(v0 & 0xFFFF0000u), w0, a1);
        a0 = fmaf(__uint_as_float(v1 << 16), w1, a0);
        a1 = fmaf(__uint_as_float(v1 & 0xFFFF0000u), w1, a1);
        a0 = fmaf(__uint_as_float(v2 << 16), w2, a0);
        a1 = fmaf(__uint_as_float(v2 & 0xFFFF0000u), w2, a1);
        a0 = fmaf(__uint_as_float(v3 << 16), w3, a0);
        a1 = fmaf(__uint_as_float(v3 & 0xFFFF0000u), w3, a1);
    }
    for (; i < deg; i += 2) {
        int s = cp[i];
        float e = as2[s] + adn;
        e = e > 0.f ? e : NEG_SLOPE * e;
        float wv = __expf(e - mm);
        ls += wv;
        if (act) {
            uint hv = *reinterpret_cast<const uint*>(h2b + (size_t)s * OUT_DIM + j * 2);
            a0 = fmaf(__uint_as_float(hv << 16), wv, a0);
            a1 = fmaf(__uint_as_float(hv & 0xFFFF0000u), wv, a1);
        }
    }
    a0 += __shfl_xor(a0, 32);
    a1 += __shfl_xor(a1, 32);
    ls += __shfl_xor(ls, 32);

    bool lead = lane < 20;
    float v0 = -INFINITY, v1 = -INFINITY;
    if (lead) {
        float2 bb = *reinterpret_cast<const float2*>(b2 + 2 * j);
        float dinv = 1.f / (ls + 1e-16f);
        v0 = a0 * dinv + bb.x;
        v1 = a1 * dinv + bb.y;
    }
    float mx = wave_reduce_max(fmaxf(v0, v1));
    float es = lead ? (__expf(v0 - mx) + __expf(v1 - mx)) : 0.f;
    float ssum = wave_reduce_sum(es);
    float lg = logf(ssum);
    if (lead) {
        float2 o2 = make_float2(v0 - mx - lg, v1 - mx - lg);
        *reinterpret_cast<float2*>(out + (size_t)n * OUT_DIM + 2 * j) = o2;
    }
}

// ---------------- launch ----------------
extern "C" void kernel_launch(void* const* d_in, const int* in_sizes, int n_in,
                              void* d_out, int out_size, void* d_ws, size_t ws_size,
                              hipStream_t stream) {
    const float* x        = (const float*)d_in[0];
    const int*   ei       = (const int*)d_in[1];
    const float* W1       = (const float*)d_in[2];
    const float* att_src1 = (const float*)d_in[3];
    const float* att_dst1 = (const float*)d_in[4];
    const float* b1       = (const float*)d_in[5];
    const float* W2       = (const float*)d_in[6];
    const float* att_src2 = (const float*)d_in[7];
    const float* att_dst2 = (const float*)d_in[8];
    const float* b2       = (const float*)d_in[9];
    float* out = (float*)d_out;

    char* ws = (char*)d_ws;
    auto alloc = [&](size_t bytes) {
        char* p = ws;
        ws += (bytes + 255) & ~(size_t)255;
        return p;
    };
    ushort* h1b    = (ushort*)alloc((size_t)M_PAD * 256 * 2);
    ushort* out1b  = (ushort*)alloc((size_t)M_PAD * 256 * 2);
    ushort* W1t    = (ushort*)alloc((size_t)256 * 256 * 2);
    ushort* W2tb   = (ushort*)alloc((size_t)48 * 264 * 2);
    ushort* h2b    = (ushort*)alloc((size_t)NNODES * OUT_DIM * 2);
    float*  as1    = (float*)alloc((size_t)NNODES * 4 * 4);
    float*  ad1    = (float*)alloc((size_t)NNODES * 4 * 4);
    float*  as2    = (float*)alloc((size_t)NNODES * 4);
    float*  ad2    = (float*)alloc((size_t)NNODES * 4);
    int*    counts = (int*)alloc((size_t)(2 * NNODES + 8) * 4);  // counts+cursor+gmax
    int*    cursor = counts + NNODES;
    uint*   gmaxb  = (uint*)(cursor + NNODES);
    int*    rowptr = (int*)alloc((size_t)(NNODES + 1) * 4);
    int*    col    = (int*)alloc((size_t)ETOT * 4);
    int*    bsum   = (int*)alloc((size_t)2 * 256 * 4);
    int*    bsum_e = bsum + 256;
    if ((size_t)(ws - (char*)d_ws) > ws_size) return;

    hipMemsetAsync(counts, 0, (size_t)(2 * NNODES + 8) * 4, stream);

    cvt_w1t_kernel<<<256, 256, 0, stream>>>(W1, W1t);
    cvt_w2t_kernel<<<(48 * 264 + 255) / 256, 256, 0, stream>>>(W2, W2tb);

    int eb = (ETOT + 255) / 256;
    count_kernel<<<eb, 256, 0, stream>>>(ei, counts);
    scanA_kernel<<<NB_SCAN, 256, 0, stream>>>(counts, rowptr, bsum);
    scanB_kernel<<<1, 256, 0, stream>>>(bsum, bsum_e);
    scanC_kernel<<<NB_SCAN, 256, 0, stream>>>(rowptr, bsum_e, cursor);
    scatter_kernel<<<eb, 256, 0, stream>>>(ei, cursor, col);

    gemm1_fused<<<M_PAD / 128, 512, 0, stream>>>(x, W1t, att_src1, att_dst1,
                                                 h1b, as1, ad1, gmaxb);
    agg1_kernel<<<NNODES / 4, 256, 0, stream>>>(h1b, as1, ad1, rowptr, col, b1, gmaxb, out1b);

    gemm2_fused<<<M_PAD / 64, 256, 0, stream>>>(out1b, W2tb, att_src2, att_dst2,
                                                h2b, as2, ad2, gmaxb);
    agg2_kernel<<<NNODES / 4, 256, 0, stream>>>(h2b, as2, ad2, rowptr, col, b2, gmaxb, out);
}